// Round 1
// baseline (3813.145 us; speedup 1.0000x reference)
//
#include <hip/hip_runtime.h>
#include <hip/hip_bf16.h>

#define N0_  320000
#define N1_  80000
#define N2_  16000
#define INC_ 128
#define HID_ 64
#define H1_  4
#define C1_  256   // H1*HID
#define OUT_ 48
#define NEG_ 0.2f

__device__ __forceinline__ float bf2f(unsigned short u){
  unsigned int v = ((unsigned int)u) << 16;
  return __uint_as_float(v);
}
__device__ __forceinline__ unsigned short f2bf(float f){
  unsigned int u = __float_as_uint(f);
  u += 0x7FFFu + ((u >> 16) & 1u);   // round-to-nearest-even
  return (unsigned short)(u >> 16);
}

// ---------------- GEMM layer 1: [M,128] @ [128,256] + b -> out ----------------
// Block 256 threads, 32 rows/block. W K-tile (32x256 f32, 32KB) + x tile (32x32) in LDS.
// Each thread: 8 rows x 4 cols micro-tile (col base = (tid&63)*4, row group = tid>>6).
__global__ __launch_bounds__(256) void gemm_k128n256(
    const float* __restrict__ X, const float* __restrict__ W,
    const float* __restrict__ bias, void* __restrict__ out,
    int M, int store_bf16)
{
  __shared__ float Ws[32][256];
  __shared__ float xs[32][32];
  const int t  = threadIdx.x;
  const int g  = t >> 6;
  const int lc = (t & 63) << 2;
  const int row0 = blockIdx.x << 5;
  float acc[8][4];
  #pragma unroll
  for (int i = 0; i < 8; ++i){ acc[i][0]=0.f; acc[i][1]=0.f; acc[i][2]=0.f; acc[i][3]=0.f; }
  const int xr = t >> 3, xk = (t & 7) << 2;
  for (int kt = 0; kt < 4; ++kt){
    const float4* Wg = (const float4*)(W + kt*32*C1_);
    float4* Wsv = (float4*)(&Ws[0][0]);
    #pragma unroll
    for (int i = 0; i < 8; ++i) Wsv[t + (i<<8)] = Wg[t + (i<<8)];
    int grow = row0 + xr;
    float4 xv = make_float4(0.f,0.f,0.f,0.f);
    if (grow < M) xv = *(const float4*)(X + (size_t)grow*INC_ + kt*32 + xk);
    *(float4*)(&xs[xr][xk]) = xv;
    __syncthreads();
    #pragma unroll 8
    for (int k = 0; k < 32; ++k){
      float4 w4 = *(const float4*)(&Ws[k][lc]);
      #pragma unroll
      for (int i = 0; i < 8; ++i){
        float xb = xs[(g<<3)+i][k];
        acc[i][0] = fmaf(xb, w4.x, acc[i][0]);
        acc[i][1] = fmaf(xb, w4.y, acc[i][1]);
        acc[i][2] = fmaf(xb, w4.z, acc[i][2]);
        acc[i][3] = fmaf(xb, w4.w, acc[i][3]);
      }
    }
    __syncthreads();
  }
  float4 b4 = *(const float4*)(bias + lc);
  #pragma unroll
  for (int i = 0; i < 8; ++i){
    int row = row0 + (g<<3) + i;
    if (row >= M) continue;
    float o0 = acc[i][0]+b4.x, o1 = acc[i][1]+b4.y, o2 = acc[i][2]+b4.z, o3 = acc[i][3]+b4.w;
    if (store_bf16){
      ushort4 s; s.x=f2bf(o0); s.y=f2bf(o1); s.z=f2bf(o2); s.w=f2bf(o3);
      *(ushort4*)((unsigned short*)out + (size_t)row*C1_ + lc) = s;
    } else {
      *(float4*)((float*)out + (size_t)row*C1_ + lc) = make_float4(o0,o1,o2,o3);
    }
  }
}

// ------------- layer-1 attention logits + exp + denom (wave per edge) -------------
// lane l: head h = l>>4, channels ci..ci+3 (ci = (l&15)*4). 16-lane group reduce per head.
__global__ __launch_bounds__(256) void edge_alpha1(
    const unsigned short* __restrict__ xl, const unsigned short* __restrict__ xr,
    const int* __restrict__ src, const int* __restrict__ dst,
    const float* __restrict__ att, float* __restrict__ aex,
    float* __restrict__ denom, int E)
{
  int wid = (blockIdx.x << 2) + (threadIdx.x >> 6);
  if (wid >= E) return;
  int lane = threadIdx.x & 63;
  int s = src[wid], d = dst[wid];
  int h = lane >> 4;
  int off = (h << 6) + ((lane & 15) << 2);
  ushort4 xv = *(const ushort4*)(xl + (size_t)s*C1_ + off);
  ushort4 rv = *(const ushort4*)(xr + (size_t)d*C1_ + off);
  float4 av = *(const float4*)(att + off);
  float e0 = bf2f(xv.x) + bf2f(rv.x); e0 = e0 > 0.f ? e0 : NEG_*e0;
  float e1 = bf2f(xv.y) + bf2f(rv.y); e1 = e1 > 0.f ? e1 : NEG_*e1;
  float e2 = bf2f(xv.z) + bf2f(rv.z); e2 = e2 > 0.f ? e2 : NEG_*e2;
  float e3 = bf2f(xv.w) + bf2f(rv.w); e3 = e3 > 0.f ? e3 : NEG_*e3;
  float p = e0*av.x + e1*av.y + e2*av.z + e3*av.w;
  p += __shfl_xor(p, 1);
  p += __shfl_xor(p, 2);
  p += __shfl_xor(p, 4);
  p += __shfl_xor(p, 8);
  if ((lane & 15) == 0){
    float ex = expf(p);           // no max-subtraction: |alpha| <~ 3.5, exp safe
    aex[(size_t)wid*H1_ + h] = ex;
    unsafeAtomicAdd(&denom[(size_t)d*H1_ + h], ex);
  }
}

// ------------- layer-1 weighted scatter: hacc[dst] += xl[src] * w  -------------
__global__ __launch_bounds__(256) void edge_scatter1(
    const unsigned short* __restrict__ xl,
    const int* __restrict__ src, const int* __restrict__ dst,
    const float* __restrict__ aex, const float* __restrict__ denom,
    float* __restrict__ hacc, int E)
{
  int wid = (blockIdx.x << 2) + (threadIdx.x >> 6);
  if (wid >= E) return;
  int lane = threadIdx.x & 63;
  int s = src[wid], d = dst[wid];
  int h = lane >> 4;
  int off = (h << 6) + ((lane & 15) << 2);
  float w = aex[(size_t)wid*H1_ + h] / (denom[(size_t)d*H1_ + h] + 1e-16f);
  ushort4 xv = *(const ushort4*)(xl + (size_t)s*C1_ + off);
  float* base = hacc + (size_t)d*C1_ + off;
  unsafeAtomicAdd(base+0, bf2f(xv.x)*w);
  unsafeAtomicAdd(base+1, bf2f(xv.y)*w);
  unsafeAtomicAdd(base+2, bf2f(xv.z)*w);
  unsafeAtomicAdd(base+3, bf2f(xv.w)*w);
}

// ------------- h = relu(hacc + bias1), in place -------------
__global__ void relu_bias_k(float* __restrict__ h, const float* __restrict__ bias, int nf4)
{
  int i = blockIdx.x*blockDim.x + threadIdx.x;
  if (i >= nf4) return;
  float4 v = ((float4*)h)[i];
  float4 b = *(const float4*)(bias + ((i & 63) << 2));
  v.x = fmaxf(v.x + b.x, 0.f);
  v.y = fmaxf(v.y + b.y, 0.f);
  v.z = fmaxf(v.z + b.z, 0.f);
  v.w = fmaxf(v.w + b.w, 0.f);
  ((float4*)h)[i] = v;
}

// ---------------- GEMM layer 2: [M,256] @ [256,48] + b -> out (one thread/output) ----------------
__global__ void gemm_k256n48(const float* __restrict__ Hin, const float* __restrict__ W,
    const float* __restrict__ bias, float* __restrict__ out, int M)
{
  int idx = blockIdx.x*blockDim.x + threadIdx.x;
  if (idx >= M*OUT_) return;
  int row = idx / OUT_;
  int col = idx - row*OUT_;
  const float* hr = Hin + (size_t)row*C1_;
  float acc = 0.f;
  #pragma unroll 8
  for (int k = 0; k < C1_; ++k) acc = fmaf(hr[k], W[k*OUT_ + col], acc);
  out[idx] = acc + bias[col];
}

// ------------- layer-2 logits + exp + denom (wave per edge, lanes 0..47) -------------
__global__ __launch_bounds__(256) void edge_alpha2(
    const float* __restrict__ xl, const float* __restrict__ xr,
    const int* __restrict__ src, const int* __restrict__ dst,
    const float* __restrict__ att, float* __restrict__ aex,
    float* __restrict__ denom, int E)
{
  int wid = (blockIdx.x << 2) + (threadIdx.x >> 6);
  if (wid >= E) return;
  int lane = threadIdx.x & 63;
  int s = src[wid], d = dst[wid];
  float p = 0.f;
  if (lane < OUT_){
    float e = xl[(size_t)s*OUT_ + lane] + xr[(size_t)d*OUT_ + lane];
    e = e > 0.f ? e : NEG_*e;
    p = e * att[lane];
  }
  #pragma unroll
  for (int o = 1; o < 64; o <<= 1) p += __shfl_xor(p, o);
  if (lane == 0){
    float ex = expf(p);
    aex[wid] = ex;
    unsafeAtomicAdd(&denom[d], ex);
  }
}

// ------------- layer-2 weighted scatter -------------
__global__ __launch_bounds__(256) void edge_scatter2(
    const float* __restrict__ xl,
    const int* __restrict__ src, const int* __restrict__ dst,
    const float* __restrict__ aex, const float* __restrict__ denom,
    float* __restrict__ acc2, int E)
{
  int wid = (blockIdx.x << 2) + (threadIdx.x >> 6);
  if (wid >= E) return;
  int lane = threadIdx.x & 63;
  int s = src[wid], d = dst[wid];
  float w = aex[wid] / (denom[d] + 1e-16f);
  if (lane < OUT_)
    unsafeAtomicAdd(&acc2[(size_t)d*OUT_ + lane], xl[(size_t)s*OUT_ + lane] * w);
}

// ------------- out = log_softmax(acc2 + bias2) (wave per row) -------------
__global__ __launch_bounds__(256) void final_logsoftmax(
    const float* __restrict__ acc2, const float* __restrict__ bias,
    float* __restrict__ out, int M)
{
  int wid = (blockIdx.x << 2) + (threadIdx.x >> 6);
  if (wid >= M) return;
  int lane = threadIdx.x & 63;
  float vv = 0.f, v = -3.0e38f;
  if (lane < OUT_){ vv = acc2[(size_t)wid*OUT_ + lane] + bias[lane]; v = vv; }
  float m = v;
  #pragma unroll
  for (int o = 1; o < 64; o <<= 1) m = fmaxf(m, __shfl_xor(m, o));
  float ex = (lane < OUT_) ? expf(vv - m) : 0.f;
  float ss = ex;
  #pragma unroll
  for (int o = 1; o < 64; o <<= 1) ss += __shfl_xor(ss, o);
  float ls = logf(ss);
  if (lane < OUT_) out[(size_t)wid*OUT_ + lane] = vv - m - ls;
}

extern "C" void kernel_launch(void* const* d_in, const int* in_sizes, int n_in,
                              void* d_out, int out_size, void* d_ws, size_t ws_size,
                              hipStream_t stream)
{
  const float* x    = (const float*)d_in[0];
  const float* Wl1  = (const float*)d_in[1];
  const float* bl1  = (const float*)d_in[2];
  const float* Wr1  = (const float*)d_in[3];
  const float* br1  = (const float*)d_in[4];
  const float* att1 = (const float*)d_in[5];
  const float* bias1= (const float*)d_in[6];
  const float* Wl2  = (const float*)d_in[7];
  const float* bl2  = (const float*)d_in[8];
  const float* Wr2  = (const float*)d_in[9];
  const float* br2  = (const float*)d_in[10];
  const float* att2 = (const float*)d_in[11];
  const float* bias2= (const float*)d_in[12];
  const int* src1 = (const int*)d_in[13];
  const int* dst1 = (const int*)d_in[14];
  const int* src2 = (const int*)d_in[15];
  const int* dst2 = (const int*)d_in[16];
  const int E1 = in_sizes[13];
  const int E2 = in_sizes[15];

  // ---- workspace layout (bytes), total 323,008,000 ----
  char* ws = (char*)d_ws;
  unsigned short* xl1 = (unsigned short*)(ws + 0LL);           // bf16 [320000][256]
  unsigned short* xr1 = (unsigned short*)(ws + 163840000LL);   // bf16 [ 80000][256]
  float* aex1 = (float*)(ws + 204800000LL);                    // f32  [800000][4]
  float* xl2  = (float*)(ws + 217600000LL);                    // f32  [ 80000][48]
  float* xr2  = (float*)(ws + 232960000LL);                    // f32  [ 16000][48]
  float* aex2 = (float*)(ws + 236032000LL);                    // f32  [160000]
  float* den1 = (float*)(ws + 236672000LL);                    // f32  [ 80000][4]   (zeroed)
  float* hbuf = (float*)(ws + 237952000LL);                    // f32  [ 80000][256] (zeroed)
  float* den2 = (float*)(ws + 319872000LL);                    // f32  [ 16000]      (zeroed)
  float* acc2 = (float*)(ws + 319936000LL);                    // f32  [ 16000][48]  (zeroed)
  (void)ws_size; (void)n_in; (void)out_size;

  // zero den1 + hbuf + den2 + acc2 (contiguous region)
  hipMemsetAsync(ws + 236672000LL, 0, 86336000LL, stream);

  gemm_k128n256<<<N0_/32, 256, 0, stream>>>(x, Wl1, bl1, (void*)xl1, N0_, 1);
  gemm_k128n256<<<N1_/32, 256, 0, stream>>>(x, Wr1, br1, (void*)xr1, N1_, 1);
  edge_alpha1  <<<(E1+3)/4, 256, 0, stream>>>(xl1, xr1, src1, dst1, att1, aex1, den1, E1);
  edge_scatter1<<<(E1+3)/4, 256, 0, stream>>>(xl1, src1, dst1, aex1, den1, hbuf, E1);
  relu_bias_k  <<<(N1_*C1_/4+255)/256, 256, 0, stream>>>(hbuf, bias1, N1_*C1_/4);
  gemm_k256n48 <<<((size_t)N1_*OUT_+255)/256, 256, 0, stream>>>(hbuf, Wl2, bl2, xl2, N1_);
  gemm_k256n48 <<<((size_t)N2_*OUT_+255)/256, 256, 0, stream>>>(hbuf, Wr2, br2, xr2, N2_);
  edge_alpha2  <<<(E2+3)/4, 256, 0, stream>>>(xl2, xr2, src2, dst2, att2, aex2, den2, E2);
  edge_scatter2<<<(E2+3)/4, 256, 0, stream>>>(xl2, src2, dst2, aex2, den2, acc2, E2);
  final_logsoftmax<<<(N2_+3)/4, 256, 0, stream>>>(acc2, bias2, (float*)d_out, N2_);
}

// Round 2
// 1101.976 us; speedup vs baseline: 3.4603x; 3.4603x over previous
//
#include <hip/hip_runtime.h>
#include <hip/hip_bf16.h>

#define N0_  320000
#define N1_  80000
#define N2_  16000
#define INC_ 128
#define HID_ 64
#define H1_  4
#define C1_  256   // H1*HID
#define OUT_ 48
#define NEG_ 0.2f

__device__ __forceinline__ float bf2f(unsigned short u){
  unsigned int v = ((unsigned int)u) << 16;
  return __uint_as_float(v);
}
__device__ __forceinline__ unsigned short f2bf(float f){
  unsigned int u = __float_as_uint(f);
  u += 0x7FFFu + ((u >> 16) & 1u);   // round-to-nearest-even
  return (unsigned short)(u >> 16);
}

// ---------------- GEMM layer 1: [M,128] @ [128,256] + b -> bf16 out ----------------
__global__ __launch_bounds__(256) void gemm_k128n256(
    const float* __restrict__ X, const float* __restrict__ W,
    const float* __restrict__ bias, unsigned short* __restrict__ out, int M)
{
  __shared__ float Ws[32][256];
  __shared__ float xs[32][32];
  const int t  = threadIdx.x;
  const int g  = t >> 6;
  const int lc = (t & 63) << 2;
  const int row0 = blockIdx.x << 5;
  float acc[8][4];
  #pragma unroll
  for (int i = 0; i < 8; ++i){ acc[i][0]=0.f; acc[i][1]=0.f; acc[i][2]=0.f; acc[i][3]=0.f; }
  const int xr = t >> 3, xk = (t & 7) << 2;
  for (int kt = 0; kt < 4; ++kt){
    const float4* Wg = (const float4*)(W + kt*32*C1_);
    float4* Wsv = (float4*)(&Ws[0][0]);
    #pragma unroll
    for (int i = 0; i < 8; ++i) Wsv[t + (i<<8)] = Wg[t + (i<<8)];
    int grow = row0 + xr;
    float4 xv = make_float4(0.f,0.f,0.f,0.f);
    if (grow < M) xv = *(const float4*)(X + (size_t)grow*INC_ + kt*32 + xk);
    *(float4*)(&xs[xr][xk]) = xv;
    __syncthreads();
    #pragma unroll 8
    for (int k = 0; k < 32; ++k){
      float4 w4 = *(const float4*)(&Ws[k][lc]);
      #pragma unroll
      for (int i = 0; i < 8; ++i){
        float xb = xs[(g<<3)+i][k];
        acc[i][0] = fmaf(xb, w4.x, acc[i][0]);
        acc[i][1] = fmaf(xb, w4.y, acc[i][1]);
        acc[i][2] = fmaf(xb, w4.z, acc[i][2]);
        acc[i][3] = fmaf(xb, w4.w, acc[i][3]);
      }
    }
    __syncthreads();
  }
  float4 b4 = *(const float4*)(bias + lc);
  #pragma unroll
  for (int i = 0; i < 8; ++i){
    int row = row0 + (g<<3) + i;
    if (row >= M) continue;
    ushort4 s; s.x=f2bf(acc[i][0]+b4.x); s.y=f2bf(acc[i][1]+b4.y);
    s.z=f2bf(acc[i][2]+b4.z); s.w=f2bf(acc[i][3]+b4.w);
    *(ushort4*)(out + (size_t)row*C1_ + lc) = s;
  }
}

// ---------------- CSR build: histogram / scan / scatter ----------------
__global__ void hist_k(const int* __restrict__ dst, int* __restrict__ counts, int E){
  int i = blockIdx.x*blockDim.x + threadIdx.x;
  if (i < E) atomicAdd(&counts[dst[i]], 1);
}

// per-block exclusive scan (chunk of 256) + block totals
__global__ __launch_bounds__(256) void scan_local(const int* __restrict__ in,
    int* __restrict__ excl, int* __restrict__ partials, int n){
  __shared__ int s[256];
  int t = threadIdx.x, i = blockIdx.x*256 + t;
  int v = (i < n) ? in[i] : 0;
  s[t] = v; __syncthreads();
  #pragma unroll
  for (int off = 1; off < 256; off <<= 1){
    int u = (t >= off) ? s[t-off] : 0;
    __syncthreads();
    s[t] += u; __syncthreads();
  }
  if (i < n) excl[i] = s[t] - v;
  if (t == 255) partials[blockIdx.x] = s[255];
}

// single-block exclusive scan of block totals (nb <= 512)
__global__ __launch_bounds__(512) void scan_partials(int* __restrict__ partials, int nb){
  __shared__ int s[512];
  int t = threadIdx.x;
  int v = (t < nb) ? partials[t] : 0;
  s[t] = v; __syncthreads();
  #pragma unroll
  for (int off = 1; off < 512; off <<= 1){
    int u = (t >= off) ? s[t-off] : 0;
    __syncthreads();
    s[t] += u; __syncthreads();
  }
  if (t < nb) partials[t] = s[t] - v;
}

__global__ void scan_finalize(int* __restrict__ excl, const int* __restrict__ partials,
    int* __restrict__ cursor, int n){
  int i = blockIdx.x*256 + threadIdx.x;
  if (i >= n) return;
  int o = excl[i] + partials[blockIdx.x];
  excl[i] = o; cursor[i] = o;
}

__global__ void scatter_k(const int* __restrict__ src, const int* __restrict__ dst,
    int* __restrict__ cursor, int* __restrict__ perm, int E){
  int i = blockIdx.x*blockDim.x + threadIdx.x;
  if (i >= E) return;
  int pos = atomicAdd(&cursor[dst[i]], 1);
  perm[pos] = src[i];
}

// ---------- fused layer-1 aggregation: wave per dst node, no atomics ----------
// alpha -> exp -> denom -> weighted sum -> /denom -> +bias -> relu, one xl read per edge
__global__ __launch_bounds__(256) void gat_aggregate1(
    const unsigned short* __restrict__ xl, const unsigned short* __restrict__ xr,
    const int* __restrict__ offsets, const int* __restrict__ counts,
    const int* __restrict__ perm, const float* __restrict__ att,
    const float* __restrict__ bias, float* __restrict__ hout, int n)
{
  int node = (blockIdx.x << 2) + (threadIdx.x >> 6);
  if (node >= n) return;
  int lane = threadIdx.x & 63;
  int off = ((lane >> 4) << 6) + ((lane & 15) << 2);  // h*64 + c
  ushort4 rv = *(const ushort4*)(xr + (size_t)node*C1_ + off);
  float r0 = bf2f(rv.x), r1 = bf2f(rv.y), r2 = bf2f(rv.z), r3 = bf2f(rv.w);
  float4 av = *(const float4*)(att + off);
  float a0 = 0.f, a1 = 0.f, a2 = 0.f, a3 = 0.f, den = 0.f;
  int st = offsets[node], cnt = counts[node];
  for (int j = 0; j < cnt; ++j){
    int s = perm[st + j];
    ushort4 xv = *(const ushort4*)(xl + (size_t)s*C1_ + off);
    float x0 = bf2f(xv.x), x1 = bf2f(xv.y), x2 = bf2f(xv.z), x3 = bf2f(xv.w);
    float e0 = x0 + r0; e0 = e0 > 0.f ? e0 : NEG_*e0;
    float e1 = x1 + r1; e1 = e1 > 0.f ? e1 : NEG_*e1;
    float e2 = x2 + r2; e2 = e2 > 0.f ? e2 : NEG_*e2;
    float e3 = x3 + r3; e3 = e3 > 0.f ? e3 : NEG_*e3;
    float p = e0*av.x + e1*av.y + e2*av.z + e3*av.w;
    p += __shfl_xor(p, 1);
    p += __shfl_xor(p, 2);
    p += __shfl_xor(p, 4);
    p += __shfl_xor(p, 8);      // all 16 lanes of the head group hold full alpha
    float ex = expf(p);         // |alpha| bounded (~3.5) -> no max-subtraction needed
    den += ex;
    a0 = fmaf(ex, x0, a0); a1 = fmaf(ex, x1, a1);
    a2 = fmaf(ex, x2, a2); a3 = fmaf(ex, x3, a3);
  }
  float w = 1.f / (den + 1e-16f);
  float4 b4 = *(const float4*)(bias + off);
  float4 o;
  o.x = fmaxf(fmaf(a0, w, b4.x), 0.f);
  o.y = fmaxf(fmaf(a1, w, b4.y), 0.f);
  o.z = fmaxf(fmaf(a2, w, b4.z), 0.f);
  o.w = fmaxf(fmaf(a3, w, b4.w), 0.f);
  *(float4*)(hout + (size_t)node*C1_ + off) = o;
}

// ---------------- GEMM layer 2: [M,256] @ [256,48] + b ----------------
__global__ void gemm_k256n48(const float* __restrict__ Hin, const float* __restrict__ W,
    const float* __restrict__ bias, float* __restrict__ out, int M)
{
  int idx = blockIdx.x*blockDim.x + threadIdx.x;
  if (idx >= M*OUT_) return;
  int row = idx / OUT_;
  int col = idx - row*OUT_;
  const float* hr = Hin + (size_t)row*C1_;
  float acc = 0.f;
  #pragma unroll 8
  for (int k = 0; k < C1_; ++k) acc = fmaf(hr[k], W[k*OUT_ + col], acc);
  out[idx] = acc + bias[col];
}

// ---------- fused layer-2 aggregation + log_softmax: wave per dst node ----------
__global__ __launch_bounds__(256) void gat_aggregate2(
    const float* __restrict__ xl, const float* __restrict__ xr,
    const int* __restrict__ offsets, const int* __restrict__ counts,
    const int* __restrict__ perm, const float* __restrict__ att,
    const float* __restrict__ bias, float* __restrict__ out, int n)
{
  int node = (blockIdx.x << 2) + (threadIdx.x >> 6);
  if (node >= n) return;
  int lane = threadIdx.x & 63;
  bool act = lane < OUT_;
  float r = act ? xr[(size_t)node*OUT_ + lane] : 0.f;
  float a = act ? att[lane] : 0.f;
  float acc = 0.f, den = 0.f;
  int st = offsets[node], cnt = counts[node];
  for (int j = 0; j < cnt; ++j){
    int s = perm[st + j];
    float xv = act ? xl[(size_t)s*OUT_ + lane] : 0.f;
    float e = xv + r; e = e > 0.f ? e : NEG_*e;
    float p = e * a;
    #pragma unroll
    for (int o = 1; o < 64; o <<= 1) p += __shfl_xor(p, o);
    float ex = expf(p);
    den += ex;
    acc = fmaf(ex, xv, acc);
  }
  float v = acc / (den + 1e-16f) + (act ? bias[lane] : 0.f);
  // log_softmax over the 48 channels
  float m = act ? v : -3.0e38f;
  #pragma unroll
  for (int o = 1; o < 64; o <<= 1) m = fmaxf(m, __shfl_xor(m, o));
  float ex = act ? expf(v - m) : 0.f;
  float ss = ex;
  #pragma unroll
  for (int o = 1; o < 64; o <<= 1) ss += __shfl_xor(ss, o);
  float ls = logf(ss);
  if (act) out[(size_t)node*OUT_ + lane] = v - m - ls;
}

extern "C" void kernel_launch(void* const* d_in, const int* in_sizes, int n_in,
                              void* d_out, int out_size, void* d_ws, size_t ws_size,
                              hipStream_t stream)
{
  const float* x    = (const float*)d_in[0];
  const float* Wl1  = (const float*)d_in[1];
  const float* bl1  = (const float*)d_in[2];
  const float* Wr1  = (const float*)d_in[3];
  const float* br1  = (const float*)d_in[4];
  const float* att1 = (const float*)d_in[5];
  const float* bias1= (const float*)d_in[6];
  const float* Wl2  = (const float*)d_in[7];
  const float* bl2  = (const float*)d_in[8];
  const float* Wr2  = (const float*)d_in[9];
  const float* br2  = (const float*)d_in[10];
  const float* att2 = (const float*)d_in[11];
  const float* bias2= (const float*)d_in[12];
  const int* src1 = (const int*)d_in[13];
  const int* dst1 = (const int*)d_in[14];
  const int* src2 = (const int*)d_in[15];
  const int* dst2 = (const int*)d_in[16];
  const int E1 = in_sizes[13];
  const int E2 = in_sizes[15];
  (void)n_in; (void)out_size; (void)ws_size;

  // ---- workspace layout (bytes), total ~310.2 MB ----
  char* ws = (char*)d_ws;
  unsigned short* xl1 = (unsigned short*)(ws + 0LL);          // bf16 [320000][256]
  unsigned short* xr1 = (unsigned short*)(ws + 163840000LL);  // bf16 [ 80000][256]
  float* hbuf   = (float*)(ws + 204800000LL);                 // f32  [ 80000][256]
  float* xl2    = (float*)(ws + 286720000LL);                 // f32  [ 80000][48]
  float* xr2    = (float*)(ws + 302080000LL);                 // f32  [ 16000][48]
  int*   perm1  = (int*)  (ws + 305152000LL);                 // int  [800000]
  int*   perm2  = (int*)  (ws + 308352000LL);                 // int  [160000]
  int*   cnt1   = (int*)  (ws + 308992000LL);                 // int  [ 80000] (zeroed)
  int*   cnt2   = (int*)  (ws + 309312000LL);                 // int  [ 16000] (zeroed)
  int*   off1   = (int*)  (ws + 309376000LL);                 // int  [ 80000]
  int*   cur1   = (int*)  (ws + 309696000LL);                 // int  [ 80000]
  int*   off2   = (int*)  (ws + 310016000LL);                 // int  [ 16000]
  int*   cur2   = (int*)  (ws + 310080000LL);                 // int  [ 16000]
  int*   part1  = (int*)  (ws + 310144000LL);                 // int  [   512]
  int*   part2  = (int*)  (ws + 310146048LL);                 // int  [   512]

  hipMemsetAsync(ws + 308992000LL, 0, 384000LL, stream);      // cnt1 + cnt2

  const int nb1 = (N1_ + 255) / 256;   // 313
  const int nb2 = (N2_ + 255) / 256;   // 63

  // layer-1 node transforms (bf16 out)
  gemm_k128n256<<<N0_/32, 256, 0, stream>>>(x, Wl1, bl1, xl1, N0_);
  gemm_k128n256<<<N1_/32, 256, 0, stream>>>(x, Wr1, br1, xr1, N1_);
  // CSR build for edge set 1
  hist_k       <<<(E1+255)/256, 256, 0, stream>>>(dst1, cnt1, E1);
  scan_local   <<<nb1, 256, 0, stream>>>(cnt1, off1, part1, N1_);
  scan_partials<<<1, 512, 0, stream>>>(part1, nb1);
  scan_finalize<<<nb1, 256, 0, stream>>>(off1, part1, cur1, N1_);
  scatter_k    <<<(E1+255)/256, 256, 0, stream>>>(src1, dst1, cur1, perm1, E1);
  // fused attention + aggregation + relu + bias
  gat_aggregate1<<<(N1_+3)/4, 256, 0, stream>>>(xl1, xr1, off1, cnt1, perm1,
                                                att1, bias1, hbuf, N1_);
  // layer-2 node transforms
  gemm_k256n48 <<<((size_t)N1_*OUT_+255)/256, 256, 0, stream>>>(hbuf, Wl2, bl2, xl2, N1_);
  gemm_k256n48 <<<((size_t)N2_*OUT_+255)/256, 256, 0, stream>>>(hbuf, Wr2, br2, xr2, N2_);
  // CSR build for edge set 2
  hist_k       <<<(E2+255)/256, 256, 0, stream>>>(dst2, cnt2, E2);
  scan_local   <<<nb2, 256, 0, stream>>>(cnt2, off2, part2, N2_);
  scan_partials<<<1, 512, 0, stream>>>(part2, nb2);
  scan_finalize<<<nb2, 256, 0, stream>>>(off2, part2, cur2, N2_);
  scatter_k    <<<(E2+255)/256, 256, 0, stream>>>(src2, dst2, cur2, perm2, E2);
  // fused attention + aggregation + log_softmax
  gat_aggregate2<<<(N2_+3)/4, 256, 0, stream>>>(xl2, xr2, off2, cnt2, perm2,
                                                att2, bias2, (float*)d_out, N2_);
}

// Round 3
// 631.706 us; speedup vs baseline: 6.0363x; 1.7444x over previous
//
#include <hip/hip_runtime.h>
#include <hip/hip_bf16.h>

#define N0_  320000
#define N1_  80000
#define N2_  16000
#define INC_ 128
#define HID_ 64
#define H1_  4
#define C1_  256   // H1*HID
#define OUT_ 48
#define NEG_ 0.2f

typedef __attribute__((ext_vector_type(8))) short bfrag8;   // 8 bf16 (4 VGPRs)
typedef __attribute__((ext_vector_type(4))) float ffrag4;   // 4 fp32 acc

__device__ __forceinline__ float bf2f(unsigned short u){
  unsigned int v = ((unsigned int)u) << 16;
  return __uint_as_float(v);
}
__device__ __forceinline__ unsigned short f2bf(float f){
  unsigned int u = __float_as_uint(f);
  u += 0x7FFFu + ((u >> 16) & 1u);   // round-to-nearest-even
  return (unsigned short)(u >> 16);
}

// ---- W [K][N] f32 -> Wt [N][K] bf16 (tiny, L2-resident thereafter) ----
__global__ void transpose_to_bf16(const float* __restrict__ W,
                                  unsigned short* __restrict__ Wt, int K, int N){
  int idx = blockIdx.x*256 + threadIdx.x;
  if (idx >= K*N) return;
  int n = idx / K, k = idx - n*K;
  Wt[idx] = f2bf(W[(size_t)k*N + n]);
}

// ---------------- MFMA GEMM1: [M,128] f32 @ Wt[256][128] bf16 + b -> bf16 [M][256] ----------------
// 256 thr / 4 waves / 64 rows per block. K=128 = 4 MFMA k-steps, fully unrolled.
// Wave w computes 64 rows x cols [w*64, w*64+64). B-frags live in registers (L2-hit loads).
__global__ __launch_bounds__(256, 3) void gemm_mfma_k128n256(
    const float* __restrict__ X, const unsigned short* __restrict__ Wt,
    const float* __restrict__ bias, unsigned short* __restrict__ out)
{
  __shared__ unsigned short As[64][136];   // +8 pad: 2-way bank aliasing only (free)
  __shared__ unsigned short Cs[64][264];   // epilogue bounce for coalesced stores
  const int t = threadIdx.x;
  const int lane = t & 63, wave = t >> 6;
  const int row0 = blockIdx.x << 6;
  const int l15 = lane & 15, q = lane >> 4;
  const int wcol = wave << 6;

  // B fragments: B[n][k0..k0+7] from transposed weights (16B loads, L2-resident)
  bfrag8 bfr[4][4];
  #pragma unroll
  for (int nt = 0; nt < 4; ++nt)
    #pragma unroll
    for (int ks = 0; ks < 4; ++ks)
      bfr[nt][ks] = *(const bfrag8*)(Wt + (size_t)(wcol + (nt<<4) + l15)*128 + (ks<<5) + (q<<3));

  // stage A tile: 64 rows x 128 k, f32 -> bf16
  const int c4 = t & 31;
  #pragma unroll
  for (int i = 0; i < 8; ++i){
    int r = (i<<3) + (t>>5);
    float4 xv = *(const float4*)(X + ((size_t)(row0 + r) << 7) + (c4<<2));
    ushort4 s; s.x=f2bf(xv.x); s.y=f2bf(xv.y); s.z=f2bf(xv.z); s.w=f2bf(xv.w);
    *(ushort4*)(&As[r][c4<<2]) = s;
  }
  __syncthreads();

  ffrag4 z = {0.f, 0.f, 0.f, 0.f};
  ffrag4 acc[4][4];
  #pragma unroll
  for (int mt = 0; mt < 4; ++mt)
    #pragma unroll
    for (int nt = 0; nt < 4; ++nt) acc[mt][nt] = z;

  #pragma unroll
  for (int mt = 0; mt < 4; ++mt){
    #pragma unroll
    for (int ks = 0; ks < 4; ++ks){
      bfrag8 af = *(const bfrag8*)(&As[(mt<<4) + l15][(ks<<5) + (q<<3)]);
      #pragma unroll
      for (int nt = 0; nt < 4; ++nt)
        acc[mt][nt] = __builtin_amdgcn_mfma_f32_16x16x32_bf16(af, bfr[nt][ks], acc[mt][nt], 0, 0, 0);
    }
  }

  // epilogue: + bias, cvt bf16, bounce via LDS, coalesced 16B stores
  float bb[4];
  #pragma unroll
  for (int nt = 0; nt < 4; ++nt) bb[nt] = bias[wcol + (nt<<4) + l15];
  #pragma unroll
  for (int mt = 0; mt < 4; ++mt)
    #pragma unroll
    for (int nt = 0; nt < 4; ++nt)
      #pragma unroll
      for (int rg = 0; rg < 4; ++rg)
        Cs[(mt<<4) + (q<<2) + rg][wcol + (nt<<4) + l15] = f2bf(acc[mt][nt][rg] + bb[nt]);
  __syncthreads();
  #pragma unroll
  for (int i = 0; i < 8; ++i){
    int r = (i<<3) + (t>>5);
    *(bfrag8*)(out + ((size_t)(row0 + r) << 8) + (c4<<3)) = *(const bfrag8*)(&Cs[r][c4<<3]);
  }
}

// ---------------- MFMA GEMM2: [M,256] bf16 @ Wt2[48][256] bf16 + b -> f32 [M][48] ----------------
// 256 thr / 4 waves / 64 rows per block; wave w handles rows [w*16, w*16+16), all 48 cols.
__global__ __launch_bounds__(256) void gemm_mfma_k256n48(
    const unsigned short* __restrict__ Hin, const unsigned short* __restrict__ Wt,
    const float* __restrict__ bias, float* __restrict__ out)
{
  __shared__ unsigned short As2[64][264];
  __shared__ unsigned short Bs2[48][264];
  const int t = threadIdx.x;
  const int lane = t & 63, wave = t >> 6;
  const int row0 = blockIdx.x << 6;
  const int l15 = lane & 15, q = lane >> 4;

  // stage A: 64 rows x 256 bf16
  const int c32 = t & 31;
  #pragma unroll
  for (int i = 0; i < 8; ++i){
    int r = (i<<3) + (t>>5);
    *(bfrag8*)(&As2[r][c32<<3]) = *(const bfrag8*)(Hin + ((size_t)(row0 + r) << 8) + (c32<<3));
  }
  // stage B: 48 x 256 bf16 (1536 chunks of 8)
  #pragma unroll
  for (int i = 0; i < 6; ++i){
    int idx = i*256 + t;
    int r = idx >> 5, c = (idx & 31) << 3;
    *(bfrag8*)(&Bs2[r][c]) = *(const bfrag8*)(Wt + (size_t)r*256 + c);
  }
  __syncthreads();

  ffrag4 z = {0.f, 0.f, 0.f, 0.f};
  ffrag4 acc[3] = {z, z, z};
  #pragma unroll
  for (int ks = 0; ks < 8; ++ks){
    bfrag8 af = *(const bfrag8*)(&As2[(wave<<4) + l15][(ks<<5) + (q<<3)]);
    #pragma unroll
    for (int nt = 0; nt < 3; ++nt){
      bfrag8 bf = *(const bfrag8*)(&Bs2[(nt<<4) + l15][(ks<<5) + (q<<3)]);
      acc[nt] = __builtin_amdgcn_mfma_f32_16x16x32_bf16(af, bf, acc[nt], 0, 0, 0);
    }
  }
  #pragma unroll
  for (int nt = 0; nt < 3; ++nt){
    int col = (nt<<4) + l15;
    float bb = bias[col];
    #pragma unroll
    for (int rg = 0; rg < 4; ++rg){
      int row = row0 + (wave<<4) + (q<<2) + rg;
      out[(size_t)row*OUT_ + col] = acc[nt][rg] + bb;
    }
  }
}

// ---------------- CSR build: histogram / scan / scatter ----------------
__global__ void hist_k(const int* __restrict__ dst, int* __restrict__ counts, int E){
  int i = blockIdx.x*blockDim.x + threadIdx.x;
  if (i < E) atomicAdd(&counts[dst[i]], 1);
}

__global__ __launch_bounds__(256) void scan_local(const int* __restrict__ in,
    int* __restrict__ excl, int* __restrict__ partials, int n){
  __shared__ int s[256];
  int t = threadIdx.x, i = blockIdx.x*256 + t;
  int v = (i < n) ? in[i] : 0;
  s[t] = v; __syncthreads();
  #pragma unroll
  for (int off = 1; off < 256; off <<= 1){
    int u = (t >= off) ? s[t-off] : 0;
    __syncthreads();
    s[t] += u; __syncthreads();
  }
  if (i < n) excl[i] = s[t] - v;
  if (t == 255) partials[blockIdx.x] = s[255];
}

__global__ __launch_bounds__(512) void scan_partials(int* __restrict__ partials, int nb){
  __shared__ int s[512];
  int t = threadIdx.x;
  int v = (t < nb) ? partials[t] : 0;
  s[t] = v; __syncthreads();
  #pragma unroll
  for (int off = 1; off < 512; off <<= 1){
    int u = (t >= off) ? s[t-off] : 0;
    __syncthreads();
    s[t] += u; __syncthreads();
  }
  if (t < nb) partials[t] = s[t] - v;
}

__global__ void scan_finalize(int* __restrict__ excl, const int* __restrict__ partials,
    int* __restrict__ cursor, int n){
  int i = blockIdx.x*256 + threadIdx.x;
  if (i >= n) return;
  int o = excl[i] + partials[blockIdx.x];
  excl[i] = o; cursor[i] = o;
}

__global__ void scatter_k(const int* __restrict__ src, const int* __restrict__ dst,
    int* __restrict__ cursor, int* __restrict__ perm, int E){
  int i = blockIdx.x*blockDim.x + threadIdx.x;
  if (i >= E) return;
  int pos = atomicAdd(&cursor[dst[i]], 1);
  perm[pos] = src[i];
}

// ---------- fused layer-1 aggregation: wave per dst node, no atomics; bf16 out ----------
__global__ __launch_bounds__(256) void gat_aggregate1(
    const unsigned short* __restrict__ xl, const unsigned short* __restrict__ xr,
    const int* __restrict__ offsets, const int* __restrict__ counts,
    const int* __restrict__ perm, const float* __restrict__ att,
    const float* __restrict__ bias, unsigned short* __restrict__ hout, int n)
{
  int node = (blockIdx.x << 2) + (threadIdx.x >> 6);
  if (node >= n) return;
  int lane = threadIdx.x & 63;
  int off = ((lane >> 4) << 6) + ((lane & 15) << 2);  // h*64 + c
  ushort4 rv = *(const ushort4*)(xr + (size_t)node*C1_ + off);
  float r0 = bf2f(rv.x), r1 = bf2f(rv.y), r2 = bf2f(rv.z), r3 = bf2f(rv.w);
  float4 av = *(const float4*)(att + off);
  float a0 = 0.f, a1 = 0.f, a2 = 0.f, a3 = 0.f, den = 0.f;
  int st = offsets[node], cnt = counts[node];
  for (int j = 0; j < cnt; ++j){
    int s = perm[st + j];
    ushort4 xv = *(const ushort4*)(xl + (size_t)s*C1_ + off);
    float x0 = bf2f(xv.x), x1 = bf2f(xv.y), x2 = bf2f(xv.z), x3 = bf2f(xv.w);
    float e0 = x0 + r0; e0 = e0 > 0.f ? e0 : NEG_*e0;
    float e1 = x1 + r1; e1 = e1 > 0.f ? e1 : NEG_*e1;
    float e2 = x2 + r2; e2 = e2 > 0.f ? e2 : NEG_*e2;
    float e3 = x3 + r3; e3 = e3 > 0.f ? e3 : NEG_*e3;
    float p = e0*av.x + e1*av.y + e2*av.z + e3*av.w;
    p += __shfl_xor(p, 1);
    p += __shfl_xor(p, 2);
    p += __shfl_xor(p, 4);
    p += __shfl_xor(p, 8);      // all 16 lanes of the head group hold full alpha
    float ex = expf(p);         // |alpha| bounded (~3.5) -> no max-subtraction needed
    den += ex;
    a0 = fmaf(ex, x0, a0); a1 = fmaf(ex, x1, a1);
    a2 = fmaf(ex, x2, a2); a3 = fmaf(ex, x3, a3);
  }
  float w = 1.f / (den + 1e-16f);
  float4 b4 = *(const float4*)(bias + off);
  ushort4 o;
  o.x = f2bf(fmaxf(fmaf(a0, w, b4.x), 0.f));
  o.y = f2bf(fmaxf(fmaf(a1, w, b4.y), 0.f));
  o.z = f2bf(fmaxf(fmaf(a2, w, b4.z), 0.f));
  o.w = f2bf(fmaxf(fmaf(a3, w, b4.w), 0.f));
  *(ushort4*)(hout + (size_t)node*C1_ + off) = o;
}

// ---------- fused layer-2 aggregation + log_softmax: wave per dst node ----------
__global__ __launch_bounds__(256) void gat_aggregate2(
    const float* __restrict__ xl, const float* __restrict__ xr,
    const int* __restrict__ offsets, const int* __restrict__ counts,
    const int* __restrict__ perm, const float* __restrict__ att,
    const float* __restrict__ bias, float* __restrict__ out, int n)
{
  int node = (blockIdx.x << 2) + (threadIdx.x >> 6);
  if (node >= n) return;
  int lane = threadIdx.x & 63;
  bool act = lane < OUT_;
  float r = act ? xr[(size_t)node*OUT_ + lane] : 0.f;
  float a = act ? att[lane] : 0.f;
  float acc = 0.f, den = 0.f;
  int st = offsets[node], cnt = counts[node];
  for (int j = 0; j < cnt; ++j){
    int s = perm[st + j];
    float xv = act ? xl[(size_t)s*OUT_ + lane] : 0.f;
    float e = xv + r; e = e > 0.f ? e : NEG_*e;
    float p = e * a;
    #pragma unroll
    for (int o = 1; o < 64; o <<= 1) p += __shfl_xor(p, o);
    float ex = expf(p);
    den += ex;
    acc = fmaf(ex, xv, acc);
  }
  float v = acc / (den + 1e-16f) + (act ? bias[lane] : 0.f);
  float m = act ? v : -3.0e38f;
  #pragma unroll
  for (int o = 1; o < 64; o <<= 1) m = fmaxf(m, __shfl_xor(m, o));
  float ex = act ? expf(v - m) : 0.f;
  float ss = ex;
  #pragma unroll
  for (int o = 1; o < 64; o <<= 1) ss += __shfl_xor(ss, o);
  float ls = logf(ss);
  if (act) out[(size_t)node*OUT_ + lane] = v - m - ls;
}

extern "C" void kernel_launch(void* const* d_in, const int* in_sizes, int n_in,
                              void* d_out, int out_size, void* d_ws, size_t ws_size,
                              hipStream_t stream)
{
  const float* x    = (const float*)d_in[0];
  const float* Wl1  = (const float*)d_in[1];
  const float* bl1  = (const float*)d_in[2];
  const float* Wr1  = (const float*)d_in[3];
  const float* br1  = (const float*)d_in[4];
  const float* att1 = (const float*)d_in[5];
  const float* bias1= (const float*)d_in[6];
  const float* Wl2  = (const float*)d_in[7];
  const float* bl2  = (const float*)d_in[8];
  const float* Wr2  = (const float*)d_in[9];
  const float* br2  = (const float*)d_in[10];
  const float* att2 = (const float*)d_in[11];
  const float* bias2= (const float*)d_in[12];
  const int* src1 = (const int*)d_in[13];
  const int* dst1 = (const int*)d_in[14];
  const int* src2 = (const int*)d_in[15];
  const int* dst2 = (const int*)d_in[16];
  const int E1 = in_sizes[13];
  const int E2 = in_sizes[15];
  (void)n_in; (void)out_size; (void)ws_size;

  // ---- workspace layout (bytes), total ~269.4 MB ----
  char* ws = (char*)d_ws;
  unsigned short* xl1  = (unsigned short*)(ws + 0LL);          // bf16 [320000][256]
  unsigned short* xr1  = (unsigned short*)(ws + 163840000LL);  // bf16 [ 80000][256]
  unsigned short* hbuf = (unsigned short*)(ws + 204800000LL);  // bf16 [ 80000][256]
  float* xl2    = (float*)(ws + 245760000LL);                  // f32  [ 80000][48]
  float* xr2    = (float*)(ws + 261120000LL);                  // f32  [ 16000][48]
  int*   perm1  = (int*)  (ws + 264192000LL);                  // int  [800000]
  int*   perm2  = (int*)  (ws + 267392000LL);                  // int  [160000]
  int*   cnt1   = (int*)  (ws + 268032000LL);                  // int  [ 80000] (zeroed)
  int*   cnt2   = (int*)  (ws + 268352000LL);                  // int  [ 16000] (zeroed)
  int*   off1   = (int*)  (ws + 268416000LL);                  // int  [ 80000]
  int*   cur1   = (int*)  (ws + 268736000LL);                  // int  [ 80000]
  int*   off2   = (int*)  (ws + 269056000LL);                  // int  [ 16000]
  int*   cur2   = (int*)  (ws + 269120000LL);                  // int  [ 16000]
  int*   part1  = (int*)  (ws + 269184000LL);                  // int  [   512]
  int*   part2  = (int*)  (ws + 269186048LL);                  // int  [   512]
  unsigned short* Wt1l = (unsigned short*)(ws + 269188096LL);  // bf16 [256][128]
  unsigned short* Wt1r = (unsigned short*)(ws + 269253632LL);  // bf16 [256][128]
  unsigned short* Wt2l = (unsigned short*)(ws + 269319168LL);  // bf16 [ 48][256]
  unsigned short* Wt2r = (unsigned short*)(ws + 269343744LL);  // bf16 [ 48][256]

  hipMemsetAsync(ws + 268032000LL, 0, 384000LL, stream);       // cnt1 + cnt2

  const int nb1 = (N1_ + 255) / 256;   // 313
  const int nb2 = (N2_ + 255) / 256;   // 63

  // weight transposes -> bf16 (tiny)
  transpose_to_bf16<<<128, 256, 0, stream>>>(Wl1, Wt1l, INC_, C1_);
  transpose_to_bf16<<<128, 256, 0, stream>>>(Wr1, Wt1r, INC_, C1_);
  transpose_to_bf16<<< 48, 256, 0, stream>>>(Wl2, Wt2l, C1_, OUT_);
  transpose_to_bf16<<< 48, 256, 0, stream>>>(Wr2, Wt2r, C1_, OUT_);

  // layer-1 node transforms (MFMA, bf16 out)
  gemm_mfma_k128n256<<<N0_/64, 256, 0, stream>>>(x, Wt1l, bl1, xl1);
  gemm_mfma_k128n256<<<N1_/64, 256, 0, stream>>>(x, Wt1r, br1, xr1);
  // CSR build for edge set 1
  hist_k       <<<(E1+255)/256, 256, 0, stream>>>(dst1, cnt1, E1);
  scan_local   <<<nb1, 256, 0, stream>>>(cnt1, off1, part1, N1_);
  scan_partials<<<1, 512, 0, stream>>>(part1, nb1);
  scan_finalize<<<nb1, 256, 0, stream>>>(off1, part1, cur1, N1_);
  scatter_k    <<<(E1+255)/256, 256, 0, stream>>>(src1, dst1, cur1, perm1, E1);
  // fused attention + aggregation + relu + bias (bf16 out)
  gat_aggregate1<<<(N1_+3)/4, 256, 0, stream>>>(xl1, xr1, off1, cnt1, perm1,
                                                att1, bias1, hbuf, N1_);
  // layer-2 node transforms (MFMA)
  gemm_mfma_k256n48<<<N1_/64, 256, 0, stream>>>(hbuf, Wt2l, bl2, xl2);
  gemm_mfma_k256n48<<<N2_/64, 256, 0, stream>>>(hbuf, Wt2r, br2, xr2);
  // CSR build for edge set 2
  hist_k       <<<(E2+255)/256, 256, 0, stream>>>(dst2, cnt2, E2);
  scan_local   <<<nb2, 256, 0, stream>>>(cnt2, off2, part2, N2_);
  scan_partials<<<1, 512, 0, stream>>>(part2, nb2);
  scan_finalize<<<nb2, 256, 0, stream>>>(off2, part2, cur2, N2_);
  scatter_k    <<<(E2+255)/256, 256, 0, stream>>>(src2, dst2, cur2, perm2, E2);
  // fused attention + aggregation + log_softmax
  gat_aggregate2<<<(N2_+3)/4, 256, 0, stream>>>(xl2, xr2, off2, cnt2, perm2,
                                                att2, bias2, (float*)d_out, N2_);
}

// Round 4
// 574.001 us; speedup vs baseline: 6.6431x; 1.1005x over previous
//
#include <hip/hip_runtime.h>
#include <hip/hip_bf16.h>

#define N0_  320000
#define N1_  80000
#define N2_  16000
#define INC_ 128
#define HID_ 64
#define H1_  4
#define C1_  256   // H1*HID
#define OUT_ 48
#define NEG_ 0.2f

typedef __attribute__((ext_vector_type(8))) short bfrag8;   // 8 bf16 (4 VGPRs)
typedef __attribute__((ext_vector_type(4))) float ffrag4;   // 4 fp32 acc

__device__ __forceinline__ float bf2f(unsigned short u){
  unsigned int v = ((unsigned int)u) << 16;
  return __uint_as_float(v);
}
__device__ __forceinline__ unsigned short f2bf(float f){
  unsigned int u = __float_as_uint(f);
  u += 0x7FFFu + ((u >> 16) & 1u);   // round-to-nearest-even
  return (unsigned short)(u >> 16);
}

// ---- W [K][N] f32 -> Wt [N][K] bf16 (tiny, L2-resident thereafter) ----
__global__ void transpose_to_bf16(const float* __restrict__ W,
                                  unsigned short* __restrict__ Wt, int K, int N){
  int idx = blockIdx.x*256 + threadIdx.x;
  if (idx >= K*N) return;
  int n = idx / K, k = idx - n*K;
  Wt[idx] = f2bf(W[(size_t)k*N + n]);
}

// ---------------- MFMA GEMM1: [M,128] f32 @ Wt[256][128] bf16 + b -> bf16 [M][256] ----------------
__global__ __launch_bounds__(256, 3) void gemm_mfma_k128n256(
    const float* __restrict__ X, const unsigned short* __restrict__ Wt,
    const float* __restrict__ bias, unsigned short* __restrict__ out)
{
  __shared__ unsigned short As[64][136];   // +8 pad: 2-way bank aliasing only (free)
  __shared__ unsigned short Cs[64][264];   // epilogue bounce for coalesced stores
  const int t = threadIdx.x;
  const int lane = t & 63, wave = t >> 6;
  const int row0 = blockIdx.x << 6;
  const int l15 = lane & 15, q = lane >> 4;
  const int wcol = wave << 6;

  bfrag8 bfr[4][4];
  #pragma unroll
  for (int nt = 0; nt < 4; ++nt)
    #pragma unroll
    for (int ks = 0; ks < 4; ++ks)
      bfr[nt][ks] = *(const bfrag8*)(Wt + (size_t)(wcol + (nt<<4) + l15)*128 + (ks<<5) + (q<<3));

  const int c4 = t & 31;
  #pragma unroll
  for (int i = 0; i < 8; ++i){
    int r = (i<<3) + (t>>5);
    float4 xv = *(const float4*)(X + ((size_t)(row0 + r) << 7) + (c4<<2));
    ushort4 s; s.x=f2bf(xv.x); s.y=f2bf(xv.y); s.z=f2bf(xv.z); s.w=f2bf(xv.w);
    *(ushort4*)(&As[r][c4<<2]) = s;
  }
  __syncthreads();

  ffrag4 z = {0.f, 0.f, 0.f, 0.f};
  ffrag4 acc[4][4];
  #pragma unroll
  for (int mt = 0; mt < 4; ++mt)
    #pragma unroll
    for (int nt = 0; nt < 4; ++nt) acc[mt][nt] = z;

  #pragma unroll
  for (int mt = 0; mt < 4; ++mt){
    #pragma unroll
    for (int ks = 0; ks < 4; ++ks){
      bfrag8 af = *(const bfrag8*)(&As[(mt<<4) + l15][(ks<<5) + (q<<3)]);
      #pragma unroll
      for (int nt = 0; nt < 4; ++nt)
        acc[mt][nt] = __builtin_amdgcn_mfma_f32_16x16x32_bf16(af, bfr[nt][ks], acc[mt][nt], 0, 0, 0);
    }
  }

  float bb[4];
  #pragma unroll
  for (int nt = 0; nt < 4; ++nt) bb[nt] = bias[wcol + (nt<<4) + l15];
  #pragma unroll
  for (int mt = 0; mt < 4; ++mt)
    #pragma unroll
    for (int nt = 0; nt < 4; ++nt)
      #pragma unroll
      for (int rg = 0; rg < 4; ++rg)
        Cs[(mt<<4) + (q<<2) + rg][wcol + (nt<<4) + l15] = f2bf(acc[mt][nt][rg] + bb[nt]);
  __syncthreads();
  #pragma unroll
  for (int i = 0; i < 8; ++i){
    int r = (i<<3) + (t>>5);
    *(bfrag8*)(out + ((size_t)(row0 + r) << 8) + (c4<<3)) = *(const bfrag8*)(&Cs[r][c4<<3]);
  }
}

// ---------------- MFMA GEMM2: [M,256] bf16 @ Wt2[48][256] bf16 + b -> f32 [M][48] ----------------
__global__ __launch_bounds__(256) void gemm_mfma_k256n48(
    const unsigned short* __restrict__ Hin, const unsigned short* __restrict__ Wt,
    const float* __restrict__ bias, float* __restrict__ out)
{
  __shared__ unsigned short As2[64][264];
  __shared__ unsigned short Bs2[48][264];
  const int t = threadIdx.x;
  const int lane = t & 63, wave = t >> 6;
  const int row0 = blockIdx.x << 6;
  const int l15 = lane & 15, q = lane >> 4;

  const int c32 = t & 31;
  #pragma unroll
  for (int i = 0; i < 8; ++i){
    int r = (i<<3) + (t>>5);
    *(bfrag8*)(&As2[r][c32<<3]) = *(const bfrag8*)(Hin + ((size_t)(row0 + r) << 8) + (c32<<3));
  }
  #pragma unroll
  for (int i = 0; i < 6; ++i){
    int idx = i*256 + t;
    int r = idx >> 5, c = (idx & 31) << 3;
    *(bfrag8*)(&Bs2[r][c]) = *(const bfrag8*)(Wt + (size_t)r*256 + c);
  }
  __syncthreads();

  ffrag4 z = {0.f, 0.f, 0.f, 0.f};
  ffrag4 acc[3] = {z, z, z};
  #pragma unroll
  for (int ks = 0; ks < 8; ++ks){
    bfrag8 af = *(const bfrag8*)(&As2[(wave<<4) + l15][(ks<<5) + (q<<3)]);
    #pragma unroll
    for (int nt = 0; nt < 3; ++nt){
      bfrag8 bf = *(const bfrag8*)(&Bs2[(nt<<4) + l15][(ks<<5) + (q<<3)]);
      acc[nt] = __builtin_amdgcn_mfma_f32_16x16x32_bf16(af, bf, acc[nt], 0, 0, 0);
    }
  }
  #pragma unroll
  for (int nt = 0; nt < 3; ++nt){
    int col = (nt<<4) + l15;
    float bb = bias[col];
    #pragma unroll
    for (int rg = 0; rg < 4; ++rg){
      int row = row0 + (wave<<4) + (q<<2) + rg;
      out[(size_t)row*OUT_ + col] = acc[nt][rg] + bb;
    }
  }
}

// ---------------- CSR build: histogram / scan / scatter ----------------
__global__ void hist_k(const int* __restrict__ dst, int* __restrict__ counts, int E){
  int i = blockIdx.x*blockDim.x + threadIdx.x;
  if (i < E) atomicAdd(&counts[dst[i]], 1);
}

__global__ __launch_bounds__(256) void scan_local(const int* __restrict__ in,
    int* __restrict__ excl, int* __restrict__ partials, int n){
  __shared__ int s[256];
  int t = threadIdx.x, i = blockIdx.x*256 + t;
  int v = (i < n) ? in[i] : 0;
  s[t] = v; __syncthreads();
  #pragma unroll
  for (int off = 1; off < 256; off <<= 1){
    int u = (t >= off) ? s[t-off] : 0;
    __syncthreads();
    s[t] += u; __syncthreads();
  }
  if (i < n) excl[i] = s[t] - v;
  if (t == 255) partials[blockIdx.x] = s[255];
}

__global__ __launch_bounds__(512) void scan_partials(int* __restrict__ partials, int nb){
  __shared__ int s[512];
  int t = threadIdx.x;
  int v = (t < nb) ? partials[t] : 0;
  s[t] = v; __syncthreads();
  #pragma unroll
  for (int off = 1; off < 512; off <<= 1){
    int u = (t >= off) ? s[t-off] : 0;
    __syncthreads();
    s[t] += u; __syncthreads();
  }
  if (t < nb) partials[t] = s[t] - v;
}

__global__ void scan_finalize(int* __restrict__ excl, const int* __restrict__ partials,
    int* __restrict__ cursor, int n){
  int i = blockIdx.x*256 + threadIdx.x;
  if (i >= n) return;
  int o = excl[i] + partials[blockIdx.x];
  excl[i] = o; cursor[i] = o;
}

__global__ void scatter_k(const int* __restrict__ src, const int* __restrict__ dst,
    int* __restrict__ cursor, int* __restrict__ perm, int E){
  int i = blockIdx.x*blockDim.x + threadIdx.x;
  if (i >= E) return;
  int pos = atomicAdd(&cursor[dst[i]], 1);
  perm[pos] = src[i];
}

// ---------- fused layer-1 aggregation: wave per dst node, pipelined gather ----------
__global__ __launch_bounds__(256) void gat_aggregate1(
    const unsigned short* __restrict__ xl, const unsigned short* __restrict__ xr,
    const int* __restrict__ offsets, const int* __restrict__ counts,
    const int* __restrict__ perm, const float* __restrict__ att,
    const float* __restrict__ bias, unsigned short* __restrict__ hout, int n)
{
  int node = (blockIdx.x << 2) + (threadIdx.x >> 6);
  if (node >= n) return;
  int lane = threadIdx.x & 63;
  int off = ((lane >> 4) << 6) + ((lane & 15) << 2);  // h*64 + c
  ushort4 rv = *(const ushort4*)(xr + (size_t)node*C1_ + off);
  float r0 = bf2f(rv.x), r1 = bf2f(rv.y), r2 = bf2f(rv.z), r3 = bf2f(rv.w);
  float4 av = *(const float4*)(att + off);
  const unsigned short* xlo = xl + off;
  float a0 = 0.f, a1 = 0.f, a2 = 0.f, a3 = 0.f, den = 0.f;
  int st = offsets[node], cnt = counts[node];

  // batch-prefetch up to 64 edge src indices with one coalesced load
  int pv = (lane < cnt) ? perm[st + lane] : 0;
  int s_cur = __shfl(pv, 0);
  ushort4 xc = make_ushort4(0,0,0,0);
  if (cnt > 0) xc = *(const ushort4*)(xlo + ((size_t)s_cur << 8));

  for (int j = 0; j < cnt; ++j){
    int jn = j + 1;
    if ((jn & 63) == 0 && jn < cnt)                 // refill index batch
      pv = ((jn + lane) < cnt) ? perm[st + jn + lane] : 0;
    int s_next = __shfl(pv, jn & 63);
    ushort4 xn = xc;
    if (jn < cnt) xn = *(const ushort4*)(xlo + ((size_t)s_next << 8));  // prefetch j+1

    float x0 = bf2f(xc.x), x1 = bf2f(xc.y), x2 = bf2f(xc.z), x3 = bf2f(xc.w);
    float v0 = x0 + r0, v1 = x1 + r1, v2 = x2 + r2, v3 = x3 + r3;
    float e0 = fmaf(NEG_, fminf(v0, 0.f), fmaxf(v0, 0.f));
    float e1 = fmaf(NEG_, fminf(v1, 0.f), fmaxf(v1, 0.f));
    float e2 = fmaf(NEG_, fminf(v2, 0.f), fmaxf(v2, 0.f));
    float e3 = fmaf(NEG_, fminf(v3, 0.f), fmaxf(v3, 0.f));
    float p = e0*av.x + e1*av.y + e2*av.z + e3*av.w;
    p += __shfl_xor(p, 1);
    p += __shfl_xor(p, 2);
    p += __shfl_xor(p, 4);
    p += __shfl_xor(p, 8);      // all 16 lanes of the head group hold full alpha
    float ex = __expf(p);       // |alpha| bounded (~4) -> native exp safe
    den += ex;
    a0 = fmaf(ex, x0, a0); a1 = fmaf(ex, x1, a1);
    a2 = fmaf(ex, x2, a2); a3 = fmaf(ex, x3, a3);
    xc = xn;
  }
  float w = 1.f / (den + 1e-16f);
  float4 b4 = *(const float4*)(bias + off);
  ushort4 o;
  o.x = f2bf(fmaxf(fmaf(a0, w, b4.x), 0.f));
  o.y = f2bf(fmaxf(fmaf(a1, w, b4.y), 0.f));
  o.z = f2bf(fmaxf(fmaf(a2, w, b4.z), 0.f));
  o.w = f2bf(fmaxf(fmaf(a3, w, b4.w), 0.f));
  *(ushort4*)(hout + (size_t)node*C1_ + off) = o;
}

// ---------- fused layer-2 aggregation + log_softmax: wave per dst node ----------
__global__ __launch_bounds__(256) void gat_aggregate2(
    const float* __restrict__ xl, const float* __restrict__ xr,
    const int* __restrict__ offsets, const int* __restrict__ counts,
    const int* __restrict__ perm, const float* __restrict__ att,
    const float* __restrict__ bias, float* __restrict__ out, int n)
{
  int node = (blockIdx.x << 2) + (threadIdx.x >> 6);
  if (node >= n) return;
  int lane = threadIdx.x & 63;
  bool act = lane < OUT_;
  float r = act ? xr[(size_t)node*OUT_ + lane] : 0.f;
  float a = act ? att[lane] : 0.f;
  float acc = 0.f, den = 0.f;
  int st = offsets[node], cnt = counts[node];

  int pv = (lane < cnt) ? perm[st + lane] : 0;
  int s_cur = __shfl(pv, 0);
  float xc = 0.f;
  if (cnt > 0 && act) xc = xl[(size_t)s_cur*OUT_ + lane];

  for (int j = 0; j < cnt; ++j){
    int jn = j + 1;
    if ((jn & 63) == 0 && jn < cnt)
      pv = ((jn + lane) < cnt) ? perm[st + jn + lane] : 0;
    int s_next = __shfl(pv, jn & 63);
    float xn = xc;
    if (jn < cnt && act) xn = xl[(size_t)s_next*OUT_ + lane];

    float v = xc + r;
    float e = fmaf(NEG_, fminf(v, 0.f), fmaxf(v, 0.f));
    float p = e * a;
    #pragma unroll
    for (int o = 1; o < 64; o <<= 1) p += __shfl_xor(p, o);
    float ex = __expf(p);
    den += ex;
    acc = fmaf(ex, xc, acc);
    xc = xn;
  }
  float v = acc / (den + 1e-16f) + (act ? bias[lane] : 0.f);
  float m = act ? v : -3.0e38f;
  #pragma unroll
  for (int o = 1; o < 64; o <<= 1) m = fmaxf(m, __shfl_xor(m, o));
  float ex = act ? __expf(v - m) : 0.f;
  float ss = ex;
  #pragma unroll
  for (int o = 1; o < 64; o <<= 1) ss += __shfl_xor(ss, o);
  float ls = __logf(ss);
  if (act) out[(size_t)node*OUT_ + lane] = v - m - ls;
}

extern "C" void kernel_launch(void* const* d_in, const int* in_sizes, int n_in,
                              void* d_out, int out_size, void* d_ws, size_t ws_size,
                              hipStream_t stream)
{
  const float* x    = (const float*)d_in[0];
  const float* Wl1  = (const float*)d_in[1];
  const float* bl1  = (const float*)d_in[2];
  const float* Wr1  = (const float*)d_in[3];
  const float* br1  = (const float*)d_in[4];
  const float* att1 = (const float*)d_in[5];
  const float* bias1= (const float*)d_in[6];
  const float* Wl2  = (const float*)d_in[7];
  const float* bl2  = (const float*)d_in[8];
  const float* Wr2  = (const float*)d_in[9];
  const float* br2  = (const float*)d_in[10];
  const float* att2 = (const float*)d_in[11];
  const float* bias2= (const float*)d_in[12];
  const int* src1 = (const int*)d_in[13];
  const int* dst1 = (const int*)d_in[14];
  const int* src2 = (const int*)d_in[15];
  const int* dst2 = (const int*)d_in[16];
  const int E1 = in_sizes[13];
  const int E2 = in_sizes[15];
  (void)n_in; (void)out_size; (void)ws_size;

  // ---- workspace layout (bytes), total ~269.4 MB ----
  char* ws = (char*)d_ws;
  unsigned short* xl1  = (unsigned short*)(ws + 0LL);          // bf16 [320000][256]
  unsigned short* xr1  = (unsigned short*)(ws + 163840000LL);  // bf16 [ 80000][256]
  unsigned short* hbuf = (unsigned short*)(ws + 204800000LL);  // bf16 [ 80000][256]
  float* xl2    = (float*)(ws + 245760000LL);                  // f32  [ 80000][48]
  float* xr2    = (float*)(ws + 261120000LL);                  // f32  [ 16000][48]
  int*   perm1  = (int*)  (ws + 264192000LL);                  // int  [800000]
  int*   perm2  = (int*)  (ws + 267392000LL);                  // int  [160000]
  int*   cnt1   = (int*)  (ws + 268032000LL);                  // int  [ 80000] (zeroed)
  int*   cnt2   = (int*)  (ws + 268352000LL);                  // int  [ 16000] (zeroed)
  int*   off1   = (int*)  (ws + 268416000LL);                  // int  [ 80000]
  int*   cur1   = (int*)  (ws + 268736000LL);                  // int  [ 80000]
  int*   off2   = (int*)  (ws + 269056000LL);                  // int  [ 16000]
  int*   cur2   = (int*)  (ws + 269120000LL);                  // int  [ 16000]
  int*   part1  = (int*)  (ws + 269184000LL);                  // int  [   512]
  int*   part2  = (int*)  (ws + 269186048LL);                  // int  [   512]
  unsigned short* Wt1l = (unsigned short*)(ws + 269188096LL);  // bf16 [256][128]
  unsigned short* Wt1r = (unsigned short*)(ws + 269253632LL);  // bf16 [256][128]
  unsigned short* Wt2l = (unsigned short*)(ws + 269319168LL);  // bf16 [ 48][256]
  unsigned short* Wt2r = (unsigned short*)(ws + 269343744LL);  // bf16 [ 48][256]

  hipMemsetAsync(ws + 268032000LL, 0, 384000LL, stream);       // cnt1 + cnt2

  const int nb1 = (N1_ + 255) / 256;   // 313
  const int nb2 = (N2_ + 255) / 256;   // 63

  transpose_to_bf16<<<128, 256, 0, stream>>>(Wl1, Wt1l, INC_, C1_);
  transpose_to_bf16<<<128, 256, 0, stream>>>(Wr1, Wt1r, INC_, C1_);
  transpose_to_bf16<<< 48, 256, 0, stream>>>(Wl2, Wt2l, C1_, OUT_);
  transpose_to_bf16<<< 48, 256, 0, stream>>>(Wr2, Wt2r, C1_, OUT_);

  gemm_mfma_k128n256<<<N0_/64, 256, 0, stream>>>(x, Wt1l, bl1, xl1);
  gemm_mfma_k128n256<<<N1_/64, 256, 0, stream>>>(x, Wt1r, br1, xr1);

  hist_k       <<<(E1+255)/256, 256, 0, stream>>>(dst1, cnt1, E1);
  scan_local   <<<nb1, 256, 0, stream>>>(cnt1, off1, part1, N1_);
  scan_partials<<<1, 512, 0, stream>>>(part1, nb1);
  scan_finalize<<<nb1, 256, 0, stream>>>(off1, part1, cur1, N1_);
  scatter_k    <<<(E1+255)/256, 256, 0, stream>>>(src1, dst1, cur1, perm1, E1);

  gat_aggregate1<<<(N1_+3)/4, 256, 0, stream>>>(xl1, xr1, off1, cnt1, perm1,
                                                att1, bias1, hbuf, N1_);

  gemm_mfma_k256n48<<<N1_/64, 256, 0, stream>>>(hbuf, Wt2l, bl2, xl2);
  gemm_mfma_k256n48<<<N2_/64, 256, 0, stream>>>(hbuf, Wt2r, br2, xr2);

  hist_k       <<<(E2+255)/256, 256, 0, stream>>>(dst2, cnt2, E2);
  scan_local   <<<nb2, 256, 0, stream>>>(cnt2, off2, part2, N2_);
  scan_partials<<<1, 512, 0, stream>>>(part2, nb2);
  scan_finalize<<<nb2, 256, 0, stream>>>(off2, part2, cur2, N2_);
  scatter_k    <<<(E2+255)/256, 256, 0, stream>>>(src2, dst2, cur2, perm2, E2);

  gat_aggregate2<<<(N2_+3)/4, 256, 0, stream>>>(xl2, xr2, off2, cnt2, perm2,
                                                att2, bias2, (float*)d_out, N2_);
}

// Round 5
// 552.255 us; speedup vs baseline: 6.9047x; 1.0394x over previous
//
#include <hip/hip_runtime.h>
#include <hip/hip_bf16.h>

#define N0_  320000
#define N1_  80000
#define N2_  16000
#define INC_ 128
#define HID_ 64
#define H1_  4
#define C1_  256   // H1*HID
#define OUT_ 48
#define OUTP_ 64   // padded layer-2 feature stride
#define NEG_ 0.2f

typedef __attribute__((ext_vector_type(8))) short bfrag8;   // 8 bf16 (4 VGPRs)
typedef __attribute__((ext_vector_type(4))) float ffrag4;   // 4 fp32 acc

__device__ __forceinline__ float bf2f(unsigned short u){
  unsigned int v = ((unsigned int)u) << 16;
  return __uint_as_float(v);
}
__device__ __forceinline__ unsigned short f2bf(float f){
  unsigned int u = __float_as_uint(f);
  u += 0x7FFFu + ((u >> 16) & 1u);   // round-to-nearest-even
  return (unsigned short)(u >> 16);
}
__device__ __forceinline__ void unpack2(unsigned int u, float& lo, float& hi){
  lo = __uint_as_float(u << 16);
  hi = __uint_as_float(u & 0xffff0000u);
}

// ---- W [K][N] f32 -> Wt [N][K] bf16 (tiny, L2-resident thereafter) ----
__global__ void transpose_to_bf16(const float* __restrict__ W,
                                  unsigned short* __restrict__ Wt, int K, int N){
  int idx = blockIdx.x*256 + threadIdx.x;
  if (idx >= K*N) return;
  int n = idx / K, k = idx - n*K;
  Wt[idx] = f2bf(W[(size_t)k*N + n]);
}

// ---------------- MFMA GEMM1: [M,128] f32 @ Wt[256][128] bf16 + b -> bf16 [M][256] ----------------
__global__ __launch_bounds__(256, 3) void gemm_mfma_k128n256(
    const float* __restrict__ X, const unsigned short* __restrict__ Wt,
    const float* __restrict__ bias, unsigned short* __restrict__ out)
{
  __shared__ unsigned short As[64][136];   // +8 pad: 2-way bank aliasing only (free)
  __shared__ unsigned short Cs[64][264];   // epilogue bounce for coalesced stores
  const int t = threadIdx.x;
  const int lane = t & 63, wave = t >> 6;
  const int row0 = blockIdx.x << 6;
  const int l15 = lane & 15, q = lane >> 4;
  const int wcol = wave << 6;

  bfrag8 bfr[4][4];
  #pragma unroll
  for (int nt = 0; nt < 4; ++nt)
    #pragma unroll
    for (int ks = 0; ks < 4; ++ks)
      bfr[nt][ks] = *(const bfrag8*)(Wt + (size_t)(wcol + (nt<<4) + l15)*128 + (ks<<5) + (q<<3));

  const int c4 = t & 31;
  #pragma unroll
  for (int i = 0; i < 8; ++i){
    int r = (i<<3) + (t>>5);
    float4 xv = *(const float4*)(X + ((size_t)(row0 + r) << 7) + (c4<<2));
    ushort4 s; s.x=f2bf(xv.x); s.y=f2bf(xv.y); s.z=f2bf(xv.z); s.w=f2bf(xv.w);
    *(ushort4*)(&As[r][c4<<2]) = s;
  }
  __syncthreads();

  ffrag4 z = {0.f, 0.f, 0.f, 0.f};
  ffrag4 acc[4][4];
  #pragma unroll
  for (int mt = 0; mt < 4; ++mt)
    #pragma unroll
    for (int nt = 0; nt < 4; ++nt) acc[mt][nt] = z;

  #pragma unroll
  for (int mt = 0; mt < 4; ++mt){
    #pragma unroll
    for (int ks = 0; ks < 4; ++ks){
      bfrag8 af = *(const bfrag8*)(&As[(mt<<4) + l15][(ks<<5) + (q<<3)]);
      #pragma unroll
      for (int nt = 0; nt < 4; ++nt)
        acc[mt][nt] = __builtin_amdgcn_mfma_f32_16x16x32_bf16(af, bfr[nt][ks], acc[mt][nt], 0, 0, 0);
    }
  }

  float bb[4];
  #pragma unroll
  for (int nt = 0; nt < 4; ++nt) bb[nt] = bias[wcol + (nt<<4) + l15];
  #pragma unroll
  for (int mt = 0; mt < 4; ++mt)
    #pragma unroll
    for (int nt = 0; nt < 4; ++nt)
      #pragma unroll
      for (int rg = 0; rg < 4; ++rg)
        Cs[(mt<<4) + (q<<2) + rg][wcol + (nt<<4) + l15] = f2bf(acc[mt][nt][rg] + bb[nt]);
  __syncthreads();
  #pragma unroll
  for (int i = 0; i < 8; ++i){
    int r = (i<<3) + (t>>5);
    *(bfrag8*)(out + ((size_t)(row0 + r) << 8) + (c4<<3)) = *(const bfrag8*)(&Cs[r][c4<<3]);
  }
}

// ------- MFMA GEMM2: [M,256] bf16 @ Wt2[48][256] bf16 + b -> f32 [M][64] (zero-padded) -------
__global__ __launch_bounds__(256) void gemm_mfma_k256n48(
    const unsigned short* __restrict__ Hin, const unsigned short* __restrict__ Wt,
    const float* __restrict__ bias, float* __restrict__ out)
{
  __shared__ unsigned short As2[64][264];
  __shared__ unsigned short Bs2[48][264];
  const int t = threadIdx.x;
  const int lane = t & 63, wave = t >> 6;
  const int row0 = blockIdx.x << 6;
  const int l15 = lane & 15, q = lane >> 4;

  const int c32 = t & 31;
  #pragma unroll
  for (int i = 0; i < 8; ++i){
    int r = (i<<3) + (t>>5);
    *(bfrag8*)(&As2[r][c32<<3]) = *(const bfrag8*)(Hin + ((size_t)(row0 + r) << 8) + (c32<<3));
  }
  #pragma unroll
  for (int i = 0; i < 6; ++i){
    int idx = i*256 + t;
    int r = idx >> 5, c = (idx & 31) << 3;
    *(bfrag8*)(&Bs2[r][c]) = *(const bfrag8*)(Wt + (size_t)r*256 + c);
  }
  __syncthreads();

  ffrag4 z = {0.f, 0.f, 0.f, 0.f};
  ffrag4 acc[3] = {z, z, z};
  #pragma unroll
  for (int ks = 0; ks < 8; ++ks){
    bfrag8 af = *(const bfrag8*)(&As2[(wave<<4) + l15][(ks<<5) + (q<<3)]);
    #pragma unroll
    for (int nt = 0; nt < 3; ++nt){
      bfrag8 bf = *(const bfrag8*)(&Bs2[(nt<<4) + l15][(ks<<5) + (q<<3)]);
      acc[nt] = __builtin_amdgcn_mfma_f32_16x16x32_bf16(af, bf, acc[nt], 0, 0, 0);
    }
  }
  #pragma unroll
  for (int nt = 0; nt < 3; ++nt){
    int col = (nt<<4) + l15;
    float bb = bias[col];
    #pragma unroll
    for (int rg = 0; rg < 4; ++rg){
      int row = row0 + (wave<<4) + (q<<2) + rg;
      out[(size_t)row*OUTP_ + col] = acc[nt][rg] + bb;
    }
  }
  // zero-fill pad cols 48..63 (agg2 relies on exact zeros)
  #pragma unroll
  for (int rg = 0; rg < 4; ++rg){
    int row = row0 + (wave<<4) + (q<<2) + rg;
    out[(size_t)row*OUTP_ + 48 + l15] = 0.f;
  }
}

// ---------------- CSR build: histogram / scan / scatter ----------------
__global__ void hist_k(const int* __restrict__ dst, int* __restrict__ counts, int E){
  int i = blockIdx.x*blockDim.x + threadIdx.x;
  if (i < E) atomicAdd(&counts[dst[i]], 1);
}

__global__ __launch_bounds__(256) void scan_local(const int* __restrict__ in,
    int* __restrict__ excl, int* __restrict__ partials, int n){
  __shared__ int s[256];
  int t = threadIdx.x, i = blockIdx.x*256 + t;
  int v = (i < n) ? in[i] : 0;
  s[t] = v; __syncthreads();
  #pragma unroll
  for (int off = 1; off < 256; off <<= 1){
    int u = (t >= off) ? s[t-off] : 0;
    __syncthreads();
    s[t] += u; __syncthreads();
  }
  if (i < n) excl[i] = s[t] - v;
  if (t == 255) partials[blockIdx.x] = s[255];
}

__global__ __launch_bounds__(512) void scan_partials(int* __restrict__ partials, int nb){
  __shared__ int s[512];
  int t = threadIdx.x;
  int v = (t < nb) ? partials[t] : 0;
  s[t] = v; __syncthreads();
  #pragma unroll
  for (int off = 1; off < 512; off <<= 1){
    int u = (t >= off) ? s[t-off] : 0;
    __syncthreads();
    s[t] += u; __syncthreads();
  }
  if (t < nb) partials[t] = s[t] - v;
}

__global__ void scan_finalize(int* __restrict__ excl, const int* __restrict__ partials,
    int* __restrict__ cursor, int n){
  int i = blockIdx.x*256 + threadIdx.x;
  if (i >= n) return;
  int o = excl[i] + partials[blockIdx.x];
  excl[i] = o; cursor[i] = o;
}

__global__ void scatter_k(const int* __restrict__ src, const int* __restrict__ dst,
    int* __restrict__ cursor, int* __restrict__ perm, int E){
  int i = blockIdx.x*blockDim.x + threadIdx.x;
  if (i >= E) return;
  int pos = atomicAdd(&cursor[dst[i]], 1);
  perm[pos] = src[i];
}

// ---------- fused layer-1 aggregation: wave/node, 2 edges per iteration ----------
// lane = slot(1b) | sub(5b); slot = edge parity, sub covers channels sub*8..sub*8+7
// (head = sub>>3 implicitly). 3-step xor reduce over the 8 lanes of a head group.
__global__ __launch_bounds__(256) void gat_aggregate1(
    const unsigned short* __restrict__ xl, const unsigned short* __restrict__ xr,
    const int* __restrict__ offsets, const int* __restrict__ counts,
    const int* __restrict__ perm, const float* __restrict__ att,
    const float* __restrict__ bias, unsigned short* __restrict__ hout, int n)
{
  int node = (blockIdx.x << 2) + (threadIdx.x >> 6);
  if (node >= n) return;
  const int lane = threadIdx.x & 63;
  const int slot = lane >> 5;          // 0 or 1
  const int sub  = lane & 31;
  const int elem = sub << 3;           // first of 8 channels
  const unsigned int ebyte = (unsigned)elem << 1;
  const char* xlb = (const char*)xl;

  // per-lane dst features (8 bf16) and att (8 f32)
  uint4 ru = *(const uint4*)(xr + ((size_t)node << 8) + elem);
  float r[8];
  unpack2(ru.x, r[0], r[1]); unpack2(ru.y, r[2], r[3]);
  unpack2(ru.z, r[4], r[5]); unpack2(ru.w, r[6], r[7]);
  float4 al = *(const float4*)(att + elem);
  float4 ah = *(const float4*)(att + elem + 4);
  float a[8] = {al.x, al.y, al.z, al.w, ah.x, ah.y, ah.z, ah.w};

  float acc[8] = {0,0,0,0,0,0,0,0};
  float den = 0.f;
  const int st = offsets[node], cnt = counts[node];

  for (int jb = 0; jb < cnt; jb += 64){
    int m = cnt - jb; if (m > 64) m = 64;
    int pv = (lane < m) ? perm[st + jb + lane] : 0;
    #pragma unroll 2
    for (int j = 0; j < m; j += 2){
      int idx = j + slot;
      int s = __shfl(pv, idx);
      uint4 xu = *(const uint4*)(xlb + (((unsigned)s << 9) + ebyte));
      float x[8];
      unpack2(xu.x, x[0], x[1]); unpack2(xu.y, x[2], x[3]);
      unpack2(xu.z, x[4], x[5]); unpack2(xu.w, x[6], x[7]);
      float p = 0.f;
      #pragma unroll
      for (int i = 0; i < 8; ++i){
        float v = x[i] + r[i];
        float e = fmaf(NEG_, fminf(v, 0.f), fmaxf(v, 0.f));
        p = fmaf(e, a[i], p);
      }
      p += __shfl_xor(p, 1);
      p += __shfl_xor(p, 2);
      p += __shfl_xor(p, 4);         // full 64-ch head dot on all 8 lanes
      float ex = __expf(p);
      ex = (idx < m) ? ex : 0.f;
      den += ex;
      #pragma unroll
      for (int i = 0; i < 8; ++i) acc[i] = fmaf(ex, x[i], acc[i]);
    }
  }
  // combine the two edge slots
  den += __shfl_xor(den, 32);
  #pragma unroll
  for (int i = 0; i < 8; ++i) acc[i] += __shfl_xor(acc[i], 32);

  if (slot == 0){
    float w = 1.f / (den + 1e-16f);
    float4 bl = *(const float4*)(bias + elem);
    float4 bh = *(const float4*)(bias + elem + 4);
    float b[8] = {bl.x, bl.y, bl.z, bl.w, bh.x, bh.y, bh.z, bh.w};
    unsigned int o[4];
    #pragma unroll
    for (int i = 0; i < 4; ++i){
      unsigned short lo = f2bf(fmaxf(fmaf(acc[2*i],   w, b[2*i]),   0.f));
      unsigned short hi = f2bf(fmaxf(fmaf(acc[2*i+1], w, b[2*i+1]), 0.f));
      o[i] = (unsigned)lo | ((unsigned)hi << 16);
    }
    *(uint4*)(hout + ((size_t)node << 8) + elem) = make_uint4(o[0], o[1], o[2], o[3]);
  }
}

// ---------- fused layer-2 aggregation + log_softmax: wave/node, 4 edges per iter ----------
// lane = slot(2b) | sub(4b); sub covers 4 channels (padded stride 64), 4-step xor reduce.
__global__ __launch_bounds__(256) void gat_aggregate2(
    const float* __restrict__ xl, const float* __restrict__ xr,   // padded [.,64]
    const int* __restrict__ offsets, const int* __restrict__ counts,
    const int* __restrict__ perm, const float* __restrict__ att,
    const float* __restrict__ bias, float* __restrict__ out, int n)
{
  int node = (blockIdx.x << 2) + (threadIdx.x >> 6);
  if (node >= n) return;
  const int lane = threadIdx.x & 63;
  const int slot = lane >> 4;          // 0..3
  const int sub  = lane & 15;          // channels sub*4..sub*4+3 (pad beyond 48)
  const bool realc = sub < 12;

  float4 r = *(const float4*)(xr + (size_t)node*OUTP_ + (sub<<2));   // pads are 0
  float4 a = realc ? *(const float4*)(att + (sub<<2)) : make_float4(0,0,0,0);
  float4 acc = make_float4(0,0,0,0);
  float den = 0.f;
  const int st = offsets[node], cnt = counts[node];

  for (int jb = 0; jb < cnt; jb += 64){
    int m = cnt - jb; if (m > 64) m = 64;
    int pv = (lane < m) ? perm[st + jb + lane] : 0;
    #pragma unroll 2
    for (int j = 0; j < m; j += 4){
      int idx = j + slot;
      int s = __shfl(pv, idx);
      float4 xv = *(const float4*)(xl + (size_t)((unsigned)s*OUTP_ + (sub<<2)));
      float v0 = xv.x + r.x, v1 = xv.y + r.y, v2 = xv.z + r.z, v3 = xv.w + r.w;
      float p;
      p = fmaf(a.x, fmaf(NEG_, fminf(v0,0.f), fmaxf(v0,0.f)), 0.f);
      p = fmaf(a.y, fmaf(NEG_, fminf(v1,0.f), fmaxf(v1,0.f)), p);
      p = fmaf(a.z, fmaf(NEG_, fminf(v2,0.f), fmaxf(v2,0.f)), p);
      p = fmaf(a.w, fmaf(NEG_, fminf(v3,0.f), fmaxf(v3,0.f)), p);
      p += __shfl_xor(p, 1);
      p += __shfl_xor(p, 2);
      p += __shfl_xor(p, 4);
      p += __shfl_xor(p, 8);
      float ex = __expf(p);
      ex = (idx < m) ? ex : 0.f;
      den += ex;
      acc.x = fmaf(ex, xv.x, acc.x); acc.y = fmaf(ex, xv.y, acc.y);
      acc.z = fmaf(ex, xv.z, acc.z); acc.w = fmaf(ex, xv.w, acc.w);
    }
  }
  // combine 4 edge slots
  den += __shfl_xor(den, 16); den += __shfl_xor(den, 32);
  acc.x += __shfl_xor(acc.x, 16); acc.x += __shfl_xor(acc.x, 32);
  acc.y += __shfl_xor(acc.y, 16); acc.y += __shfl_xor(acc.y, 32);
  acc.z += __shfl_xor(acc.z, 16); acc.z += __shfl_xor(acc.z, 32);
  acc.w += __shfl_xor(acc.w, 16); acc.w += __shfl_xor(acc.w, 32);

  float w = 1.f / (den + 1e-16f);
  float4 b = realc ? *(const float4*)(bias + (sub<<2)) : make_float4(0,0,0,0);
  float v0 = fmaf(acc.x, w, b.x), v1 = fmaf(acc.y, w, b.y);
  float v2 = fmaf(acc.z, w, b.z), v3 = fmaf(acc.w, w, b.w);

  // log-softmax over 48 channels (reduce within the 16-lane slot group; all slots identical)
  float mx = realc ? fmaxf(fmaxf(v0, v1), fmaxf(v2, v3)) : -3.0e38f;
  mx = fmaxf(mx, __shfl_xor(mx, 1)); mx = fmaxf(mx, __shfl_xor(mx, 2));
  mx = fmaxf(mx, __shfl_xor(mx, 4)); mx = fmaxf(mx, __shfl_xor(mx, 8));
  float es = realc ? (__expf(v0-mx) + __expf(v1-mx) + __expf(v2-mx) + __expf(v3-mx)) : 0.f;
  es += __shfl_xor(es, 1); es += __shfl_xor(es, 2);
  es += __shfl_xor(es, 4); es += __shfl_xor(es, 8);
  float ls = __logf(es);
  if (slot == 0 && realc){
    float4 o = make_float4(v0-mx-ls, v1-mx-ls, v2-mx-ls, v3-mx-ls);
    *(float4*)(out + (size_t)node*OUT_ + (sub<<2)) = o;
  }
}

extern "C" void kernel_launch(void* const* d_in, const int* in_sizes, int n_in,
                              void* d_out, int out_size, void* d_ws, size_t ws_size,
                              hipStream_t stream)
{
  const float* x    = (const float*)d_in[0];
  const float* Wl1  = (const float*)d_in[1];
  const float* bl1  = (const float*)d_in[2];
  const float* Wr1  = (const float*)d_in[3];
  const float* br1  = (const float*)d_in[4];
  const float* att1 = (const float*)d_in[5];
  const float* bias1= (const float*)d_in[6];
  const float* Wl2  = (const float*)d_in[7];
  const float* bl2  = (const float*)d_in[8];
  const float* Wr2  = (const float*)d_in[9];
  const float* br2  = (const float*)d_in[10];
  const float* att2 = (const float*)d_in[11];
  const float* bias2= (const float*)d_in[12];
  const int* src1 = (const int*)d_in[13];
  const int* dst1 = (const int*)d_in[14];
  const int* src2 = (const int*)d_in[15];
  const int* dst2 = (const int*)d_in[16];
  const int E1 = in_sizes[13];
  const int E2 = in_sizes[15];
  (void)n_in; (void)out_size; (void)ws_size;

  // ---- workspace layout (bytes), total ~275.5 MB ----
  char* ws = (char*)d_ws;
  unsigned short* xl1  = (unsigned short*)(ws + 0LL);          // bf16 [320000][256]
  unsigned short* xr1  = (unsigned short*)(ws + 163840000LL);  // bf16 [ 80000][256]
  unsigned short* hbuf = (unsigned short*)(ws + 204800000LL);  // bf16 [ 80000][256]
  float* xl2p   = (float*)(ws + 245760000LL);                  // f32  [ 80000][64] padded
  float* xr2p   = (float*)(ws + 266240000LL);                  // f32  [ 16000][64] padded
  int*   perm1  = (int*)  (ws + 270336000LL);                  // int  [800000]
  int*   perm2  = (int*)  (ws + 273536000LL);                  // int  [160000]
  int*   cnt1   = (int*)  (ws + 274176000LL);                  // int  [ 80000] (zeroed)
  int*   cnt2   = (int*)  (ws + 274496000LL);                  // int  [ 16000] (zeroed)
  int*   off1   = (int*)  (ws + 274560000LL);                  // int  [ 80000]
  int*   cur1   = (int*)  (ws + 274880000LL);                  // int  [ 80000]
  int*   off2   = (int*)  (ws + 275200000LL);                  // int  [ 16000]
  int*   cur2   = (int*)  (ws + 275264000LL);                  // int  [ 16000]
  int*   part1  = (int*)  (ws + 275328000LL);                  // int  [   512]
  int*   part2  = (int*)  (ws + 275330048LL);                  // int  [   512]
  unsigned short* Wt1l = (unsigned short*)(ws + 275332096LL);  // bf16 [256][128]
  unsigned short* Wt1r = (unsigned short*)(ws + 275397632LL);  // bf16 [256][128]
  unsigned short* Wt2l = (unsigned short*)(ws + 275463168LL);  // bf16 [ 48][256]
  unsigned short* Wt2r = (unsigned short*)(ws + 275487744LL);  // bf16 [ 48][256]

  hipMemsetAsync(ws + 274176000LL, 0, 384000LL, stream);       // cnt1 + cnt2

  const int nb1 = (N1_ + 255) / 256;   // 313
  const int nb2 = (N2_ + 255) / 256;   // 63

  transpose_to_bf16<<<128, 256, 0, stream>>>(Wl1, Wt1l, INC_, C1_);
  transpose_to_bf16<<<128, 256, 0, stream>>>(Wr1, Wt1r, INC_, C1_);
  transpose_to_bf16<<< 48, 256, 0, stream>>>(Wl2, Wt2l, C1_, OUT_);
  transpose_to_bf16<<< 48, 256, 0, stream>>>(Wr2, Wt2r, C1_, OUT_);

  gemm_mfma_k128n256<<<N0_/64, 256, 0, stream>>>(x, Wt1l, bl1, xl1);
  gemm_mfma_k128n256<<<N1_/64, 256, 0, stream>>>(x, Wt1r, br1, xr1);

  hist_k       <<<(E1+255)/256, 256, 0, stream>>>(dst1, cnt1, E1);
  scan_local   <<<nb1, 256, 0, stream>>>(cnt1, off1, part1, N1_);
  scan_partials<<<1, 512, 0, stream>>>(part1, nb1);
  scan_finalize<<<nb1, 256, 0, stream>>>(off1, part1, cur1, N1_);
  scatter_k    <<<(E1+255)/256, 256, 0, stream>>>(src1, dst1, cur1, perm1, E1);

  gat_aggregate1<<<(N1_+3)/4, 256, 0, stream>>>(xl1, xr1, off1, cnt1, perm1,
                                                att1, bias1, hbuf, N1_);

  gemm_mfma_k256n48<<<N1_/64, 256, 0, stream>>>(hbuf, Wt2l, bl2, xl2p);
  gemm_mfma_k256n48<<<N2_/64, 256, 0, stream>>>(hbuf, Wt2r, br2, xr2p);

  hist_k       <<<(E2+255)/256, 256, 0, stream>>>(dst2, cnt2, E2);
  scan_local   <<<nb2, 256, 0, stream>>>(cnt2, off2, part2, N2_);
  scan_partials<<<1, 512, 0, stream>>>(part2, nb2);
  scan_finalize<<<nb2, 256, 0, stream>>>(off2, part2, cur2, N2_);
  scatter_k    <<<(E2+255)/256, 256, 0, stream>>>(src2, dst2, cur2, perm2, E2);

  gat_aggregate2<<<(N2_+3)/4, 256, 0, stream>>>(xl2p, xr2p, off2, cnt2, perm2,
                                                att2, bias2, (float*)d_out, N2_);
}

// Round 6
// 535.212 us; speedup vs baseline: 7.1246x; 1.0318x over previous
//
#include <hip/hip_runtime.h>
#include <hip/hip_bf16.h>

#define N0_  320000
#define N1_  80000
#define N2_  16000
#define INC_ 128
#define HID_ 64
#define H1_  4
#define C1_  256   // H1*HID
#define OUT_ 48
#define OUTP_ 64   // padded layer-2 feature stride
#define NEG_ 0.2f

typedef __attribute__((ext_vector_type(8))) short bfrag8;   // 8 bf16 (4 VGPRs)
typedef __attribute__((ext_vector_type(4))) float ffrag4;   // 4 fp32 acc

__device__ __forceinline__ float bf2f(unsigned short u){
  unsigned int v = ((unsigned int)u) << 16;
  return __uint_as_float(v);
}
__device__ __forceinline__ unsigned short f2bf(float f){
  unsigned int u = __float_as_uint(f);
  u += 0x7FFFu + ((u >> 16) & 1u);   // round-to-nearest-even
  return (unsigned short)(u >> 16);
}
__device__ __forceinline__ void unpack2(unsigned int u, float& lo, float& hi){
  lo = __uint_as_float(u << 16);
  hi = __uint_as_float(u & 0xffff0000u);
}

// ---- all 4 weight transposes in one kernel (f32 [K][N] -> bf16 [N][K]) ----
__global__ void transpose_all(const float* __restrict__ Wl1, const float* __restrict__ Wr1,
                              const float* __restrict__ Wl2, const float* __restrict__ Wr2,
                              unsigned short* __restrict__ Wt1l, unsigned short* __restrict__ Wt1r,
                              unsigned short* __restrict__ Wt2l, unsigned short* __restrict__ Wt2r){
  int idx = blockIdx.x*256 + threadIdx.x;
  if (idx < 32768){ int n = idx >> 7, k = idx & 127; Wt1l[idx] = f2bf(Wl1[k*C1_ + n]); }
  else if (idx < 65536){ int j = idx - 32768; int n = j >> 7, k = j & 127; Wt1r[j] = f2bf(Wr1[k*C1_ + n]); }
  else if (idx < 77824){ int j = idx - 65536; int n = j >> 8, k = j & 255; Wt2l[j] = f2bf(Wl2[k*OUT_ + n]); }
  else if (idx < 90112){ int j = idx - 77824; int n = j >> 8, k = j & 255; Wt2r[j] = f2bf(Wr2[k*OUT_ + n]); }
}

// ------- fused GEMM1: stage A once; pass0 -> xl1 (all rows), pass1 -> xr1 (rows < N1) -------
__global__ __launch_bounds__(256, 3) void gemm1_fused(
    const float* __restrict__ X,
    const unsigned short* __restrict__ Wtl, const unsigned short* __restrict__ Wtr,
    const float* __restrict__ bl, const float* __restrict__ br,
    unsigned short* __restrict__ outl, unsigned short* __restrict__ outr)
{
  __shared__ unsigned short As[64][136];   // +8 pad: 2-way bank aliasing only (free)
  __shared__ unsigned short Cs[64][264];   // epilogue bounce for coalesced stores
  const int t = threadIdx.x;
  const int lane = t & 63, wave = t >> 6;
  const int row0 = blockIdx.x << 6;
  const int l15 = lane & 15, q = lane >> 4;
  const int wcol = wave << 6;
  const int c4 = t & 31;

  #pragma unroll
  for (int i = 0; i < 8; ++i){
    int r = (i<<3) + (t>>5);
    float4 xv = *(const float4*)(X + ((size_t)(row0 + r) << 7) + (c4<<2));
    ushort4 s; s.x=f2bf(xv.x); s.y=f2bf(xv.y); s.z=f2bf(xv.z); s.w=f2bf(xv.w);
    *(ushort4*)(&As[r][c4<<2]) = s;
  }
  __syncthreads();

  const int npass = (row0 < N1_) ? 2 : 1;
  for (int pass = 0; pass < npass; ++pass){
    const unsigned short* Wt = pass ? Wtr : Wtl;
    const float* bias = pass ? br : bl;
    unsigned short* out = pass ? outr : outl;

    bfrag8 bfr[4][4];
    #pragma unroll
    for (int nt = 0; nt < 4; ++nt)
      #pragma unroll
      for (int ks = 0; ks < 4; ++ks)
        bfr[nt][ks] = *(const bfrag8*)(Wt + (size_t)(wcol + (nt<<4) + l15)*128 + (ks<<5) + (q<<3));

    ffrag4 z = {0.f, 0.f, 0.f, 0.f};
    ffrag4 acc[4][4];
    #pragma unroll
    for (int mt = 0; mt < 4; ++mt)
      #pragma unroll
      for (int nt = 0; nt < 4; ++nt) acc[mt][nt] = z;

    #pragma unroll
    for (int mt = 0; mt < 4; ++mt){
      #pragma unroll
      for (int ks = 0; ks < 4; ++ks){
        bfrag8 af = *(const bfrag8*)(&As[(mt<<4) + l15][(ks<<5) + (q<<3)]);
        #pragma unroll
        for (int nt = 0; nt < 4; ++nt)
          acc[mt][nt] = __builtin_amdgcn_mfma_f32_16x16x32_bf16(af, bfr[nt][ks], acc[mt][nt], 0, 0, 0);
      }
    }

    float bb[4];
    #pragma unroll
    for (int nt = 0; nt < 4; ++nt) bb[nt] = bias[wcol + (nt<<4) + l15];
    #pragma unroll
    for (int mt = 0; mt < 4; ++mt)
      #pragma unroll
      for (int nt = 0; nt < 4; ++nt)
        #pragma unroll
        for (int rg = 0; rg < 4; ++rg)
          Cs[(mt<<4) + (q<<2) + rg][wcol + (nt<<4) + l15] = f2bf(acc[mt][nt][rg] + bb[nt]);
    __syncthreads();
    #pragma unroll
    for (int i = 0; i < 8; ++i){
      int r = (i<<3) + (t>>5);
      *(bfrag8*)(out + ((size_t)(row0 + r) << 8) + (c4<<3)) = *(const bfrag8*)(&Cs[r][c4<<3]);
    }
    if (pass + 1 < npass) __syncthreads();   // protect Cs reuse
  }
}

// ------- fused GEMM2: [M,256] bf16 @ Wt2[48][256] + b -> f32 [M][64] zero-padded -------
__global__ __launch_bounds__(256) void gemm2_fused(
    const unsigned short* __restrict__ Hin,
    const unsigned short* __restrict__ Wtl, const unsigned short* __restrict__ Wtr,
    const float* __restrict__ bl, const float* __restrict__ br,
    float* __restrict__ outl, float* __restrict__ outr)
{
  __shared__ unsigned short As2[64][264];
  __shared__ unsigned short Bs2[48][264];
  const int t = threadIdx.x;
  const int lane = t & 63, wave = t >> 6;
  const int row0 = blockIdx.x << 6;
  const int l15 = lane & 15, q = lane >> 4;
  const int c32 = t & 31;

  #pragma unroll
  for (int i = 0; i < 8; ++i){
    int r = (i<<3) + (t>>5);
    *(bfrag8*)(&As2[r][c32<<3]) = *(const bfrag8*)(Hin + ((size_t)(row0 + r) << 8) + (c32<<3));
  }

  const int npass = (row0 < N2_) ? 2 : 1;
  for (int pass = 0; pass < npass; ++pass){
    const unsigned short* Wt = pass ? Wtr : Wtl;
    const float* bias = pass ? br : bl;
    float* out = pass ? outr : outl;

    if (pass) __syncthreads();          // prior mfma done before Bs2 overwrite
    #pragma unroll
    for (int i = 0; i < 6; ++i){
      int idx = i*256 + t;
      int r = idx >> 5, c = (idx & 31) << 3;
      *(bfrag8*)(&Bs2[r][c]) = *(const bfrag8*)(Wt + (size_t)r*256 + c);
    }
    __syncthreads();                    // also covers As2 staging on pass 0

    ffrag4 z = {0.f, 0.f, 0.f, 0.f};
    ffrag4 acc[3] = {z, z, z};
    #pragma unroll
    for (int ks = 0; ks < 8; ++ks){
      bfrag8 af = *(const bfrag8*)(&As2[(wave<<4) + l15][(ks<<5) + (q<<3)]);
      #pragma unroll
      for (int nt = 0; nt < 3; ++nt){
        bfrag8 bf = *(const bfrag8*)(&Bs2[(nt<<4) + l15][(ks<<5) + (q<<3)]);
        acc[nt] = __builtin_amdgcn_mfma_f32_16x16x32_bf16(af, bf, acc[nt], 0, 0, 0);
      }
    }
    #pragma unroll
    for (int nt = 0; nt < 3; ++nt){
      int col = (nt<<4) + l15;
      float bb = bias[col];
      #pragma unroll
      for (int rg = 0; rg < 4; ++rg){
        int row = row0 + (wave<<4) + (q<<2) + rg;
        out[(size_t)row*OUTP_ + col] = acc[nt][rg] + bb;
      }
    }
    #pragma unroll
    for (int rg = 0; rg < 4; ++rg){     // zero pad cols 48..63
      int row = row0 + (wave<<4) + (q<<2) + rg;
      out[(size_t)row*OUTP_ + 48 + l15] = 0.f;
    }
  }
}

// ---------------- CSR build (both edge sets per kernel) ----------------
__global__ void hist_both(const int* __restrict__ dst1, const int* __restrict__ dst2,
                          int* __restrict__ cnt1, int* __restrict__ cnt2, int E1, int E2){
  int i = blockIdx.x*256 + threadIdx.x;
  if (i < E1) atomicAdd(&cnt1[dst1[i]], 1);
  else if (i < E1 + E2) atomicAdd(&cnt2[dst2[i - E1]], 1);
}

__global__ __launch_bounds__(256) void scan_local_both(
    const int* __restrict__ in1, const int* __restrict__ in2,
    int* __restrict__ ex1, int* __restrict__ ex2,
    int* __restrict__ part1, int* __restrict__ part2, int n1, int n2, int nb1){
  __shared__ int s[256];
  const int* in; int* excl; int* partials; int n; int b;
  if ((int)blockIdx.x < nb1){ in = in1; excl = ex1; partials = part1; n = n1; b = blockIdx.x; }
  else { in = in2; excl = ex2; partials = part2; n = n2; b = blockIdx.x - nb1; }
  int t = threadIdx.x, i = b*256 + t;
  int v = (i < n) ? in[i] : 0;
  s[t] = v; __syncthreads();
  #pragma unroll
  for (int off = 1; off < 256; off <<= 1){
    int u = (t >= off) ? s[t-off] : 0;
    __syncthreads();
    s[t] += u; __syncthreads();
  }
  if (i < n) excl[i] = s[t] - v;
  if (t == 255) partials[b] = s[255];
}

__global__ __launch_bounds__(512) void scan_partials_both(
    int* __restrict__ part1, int* __restrict__ part2, int nb1, int nb2){
  __shared__ int s[512];
  int* partials = blockIdx.x ? part2 : part1;
  int nb = blockIdx.x ? nb2 : nb1;
  int t = threadIdx.x;
  int v = (t < nb) ? partials[t] : 0;
  s[t] = v; __syncthreads();
  #pragma unroll
  for (int off = 1; off < 512; off <<= 1){
    int u = (t >= off) ? s[t-off] : 0;
    __syncthreads();
    s[t] += u; __syncthreads();
  }
  if (t < nb) partials[t] = s[t] - v;
}

__global__ void scan_finalize_both(
    int* __restrict__ ex1, int* __restrict__ ex2,
    const int* __restrict__ part1, const int* __restrict__ part2,
    int* __restrict__ cur1, int* __restrict__ cur2, int n1, int n2, int nb1){
  int* excl; const int* partials; int* cursor; int n; int b;
  if ((int)blockIdx.x < nb1){ excl = ex1; partials = part1; cursor = cur1; n = n1; b = blockIdx.x; }
  else { excl = ex2; partials = part2; cursor = cur2; n = n2; b = blockIdx.x - nb1; }
  int i = b*256 + threadIdx.x;
  if (i >= n) return;
  int o = excl[i] + partials[b];
  excl[i] = o; cursor[i] = o;
}

__global__ void scatter_both(const int* __restrict__ src1, const int* __restrict__ dst1,
                             const int* __restrict__ src2, const int* __restrict__ dst2,
                             int* __restrict__ cur1, int* __restrict__ cur2,
                             int* __restrict__ perm1, int* __restrict__ perm2, int E1, int E2){
  int i = blockIdx.x*256 + threadIdx.x;
  if (i < E1){
    int pos = atomicAdd(&cur1[dst1[i]], 1);
    perm1[pos] = src1[i];
  } else if (i < E1 + E2){
    int j = i - E1;
    int pos = atomicAdd(&cur2[dst2[j]], 1);
    perm2[pos] = src2[j];
  }
}

// ---------- fused layer-1 aggregation: wave/node, 2 edges/iter, 1-ahead gather prefetch ----------
__global__ __launch_bounds__(256) void gat_aggregate1(
    const unsigned short* __restrict__ xl, const unsigned short* __restrict__ xr,
    const int* __restrict__ offsets, const int* __restrict__ counts,
    const int* __restrict__ perm, const float* __restrict__ att,
    const float* __restrict__ bias, unsigned short* __restrict__ hout, int n)
{
  int node = (blockIdx.x << 2) + (threadIdx.x >> 6);
  if (node >= n) return;
  const int lane = threadIdx.x & 63;
  const int slot = lane >> 5;          // edge parity
  const int sub  = lane & 31;
  const int elem = sub << 3;           // 8 channels per lane (head = sub>>3)
  const unsigned int ebyte = (unsigned)elem << 1;
  const char* xlb = (const char*)xl;

  const int st = offsets[node], cnt = counts[node];
  uint4 ru = *(const uint4*)(xr + ((size_t)node << 8) + elem);
  float r[8];
  unpack2(ru.x, r[0], r[1]); unpack2(ru.y, r[2], r[3]);
  unpack2(ru.z, r[4], r[5]); unpack2(ru.w, r[6], r[7]);
  float4 al = *(const float4*)(att + elem);
  float4 ah = *(const float4*)(att + elem + 4);
  float a[8] = {al.x, al.y, al.z, al.w, ah.x, ah.y, ah.z, ah.w};

  float acc[8] = {0,0,0,0,0,0,0,0};
  float den = 0.f;

  for (int jb = 0; jb < cnt; jb += 64){
    int m = cnt - jb; if (m > 64) m = 64;
    int pv = (lane < m) ? perm[st + jb + lane] : 0;
    int s_cur = __shfl(pv, slot);
    uint4 xc = *(const uint4*)(xlb + (((unsigned)s_cur << 9) + ebyte));
    for (int j = 0; j < m; j += 2){
      int s_next = __shfl(pv, (j + 2 + slot) & 63);     // out-of-range -> pv=0 lanes (safe)
      uint4 xn = *(const uint4*)(xlb + (((unsigned)s_next << 9) + ebyte));  // prefetch j+2
      float x[8];
      unpack2(xc.x, x[0], x[1]); unpack2(xc.y, x[2], x[3]);
      unpack2(xc.z, x[4], x[5]); unpack2(xc.w, x[6], x[7]);
      float p = 0.f;
      #pragma unroll
      for (int i = 0; i < 8; ++i){
        float v = x[i] + r[i];
        float e = fmaf(NEG_, fminf(v, 0.f), fmaxf(v, 0.f));
        p = fmaf(e, a[i], p);
      }
      p += __shfl_xor(p, 1);
      p += __shfl_xor(p, 2);
      p += __shfl_xor(p, 4);         // full 64-ch head dot on all 8 lanes
      float ex = __expf(p);          // |alpha| bounded -> native exp safe
      ex = (j + slot < m) ? ex : 0.f;
      den += ex;
      #pragma unroll
      for (int i = 0; i < 8; ++i) acc[i] = fmaf(ex, x[i], acc[i]);
      xc = xn;
    }
  }
  den += __shfl_xor(den, 32);
  #pragma unroll
  for (int i = 0; i < 8; ++i) acc[i] += __shfl_xor(acc[i], 32);

  if (slot == 0){
    float w = 1.f / (den + 1e-16f);
    float4 bl = *(const float4*)(bias + elem);
    float4 bh = *(const float4*)(bias + elem + 4);
    float b[8] = {bl.x, bl.y, bl.z, bl.w, bh.x, bh.y, bh.z, bh.w};
    unsigned int o[4];
    #pragma unroll
    for (int i = 0; i < 4; ++i){
      unsigned short lo = f2bf(fmaxf(fmaf(acc[2*i],   w, b[2*i]),   0.f));
      unsigned short hi = f2bf(fmaxf(fmaf(acc[2*i+1], w, b[2*i+1]), 0.f));
      o[i] = (unsigned)lo | ((unsigned)hi << 16);
    }
    *(uint4*)(hout + ((size_t)node << 8) + elem) = make_uint4(o[0], o[1], o[2], o[3]);
  }
}

// ---------- fused layer-2 aggregation + log_softmax: wave/node, 4 edges/iter, prefetch ----------
__global__ __launch_bounds__(256) void gat_aggregate2(
    const float* __restrict__ xl, const float* __restrict__ xr,   // padded [.,64]
    const int* __restrict__ offsets, const int* __restrict__ counts,
    const int* __restrict__ perm, const float* __restrict__ att,
    const float* __restrict__ bias, float* __restrict__ out, int n)
{
  int node = (blockIdx.x << 2) + (threadIdx.x >> 6);
  if (node >= n) return;
  const int lane = threadIdx.x & 63;
  const int slot = lane >> 4;          // 0..3
  const int sub  = lane & 15;          // 4 channels (pad beyond 48)
  const bool realc = sub < 12;

  const int st = offsets[node], cnt = counts[node];
  float4 r = *(const float4*)(xr + (size_t)node*OUTP_ + (sub<<2));   // pads are 0
  float4 a = realc ? *(const float4*)(att + (sub<<2)) : make_float4(0,0,0,0);
  float4 acc = make_float4(0,0,0,0);
  float den = 0.f;

  for (int jb = 0; jb < cnt; jb += 64){
    int m = cnt - jb; if (m > 64) m = 64;
    int pv = (lane < m) ? perm[st + jb + lane] : 0;
    int s_cur = __shfl(pv, slot);
    float4 xc = *(const float4*)(xl + (size_t)((unsigned)s_cur*OUTP_ + (sub<<2)));
    for (int j = 0; j < m; j += 4){
      int s_next = __shfl(pv, (j + 4 + slot) & 63);
      float4 xn = *(const float4*)(xl + (size_t)((unsigned)s_next*OUTP_ + (sub<<2)));
      float v0 = xc.x + r.x, v1 = xc.y + r.y, v2 = xc.z + r.z, v3 = xc.w + r.w;
      float p;
      p = fmaf(a.x, fmaf(NEG_, fminf(v0,0.f), fmaxf(v0,0.f)), 0.f);
      p = fmaf(a.y, fmaf(NEG_, fminf(v1,0.f), fmaxf(v1,0.f)), p);
      p = fmaf(a.z, fmaf(NEG_, fminf(v2,0.f), fmaxf(v2,0.f)), p);
      p = fmaf(a.w, fmaf(NEG_, fminf(v3,0.f), fmaxf(v3,0.f)), p);
      p += __shfl_xor(p, 1);
      p += __shfl_xor(p, 2);
      p += __shfl_xor(p, 4);
      p += __shfl_xor(p, 8);
      float ex = __expf(p);
      ex = (j + slot < m) ? ex : 0.f;
      den += ex;
      acc.x = fmaf(ex, xc.x, acc.x); acc.y = fmaf(ex, xc.y, acc.y);
      acc.z = fmaf(ex, xc.z, acc.z); acc.w = fmaf(ex, xc.w, acc.w);
      xc = xn;
    }
  }
  den += __shfl_xor(den, 16); den += __shfl_xor(den, 32);
  acc.x += __shfl_xor(acc.x, 16); acc.x += __shfl_xor(acc.x, 32);
  acc.y += __shfl_xor(acc.y, 16); acc.y += __shfl_xor(acc.y, 32);
  acc.z += __shfl_xor(acc.z, 16); acc.z += __shfl_xor(acc.z, 32);
  acc.w += __shfl_xor(acc.w, 16); acc.w += __shfl_xor(acc.w, 32);

  float w = 1.f / (den + 1e-16f);
  float4 b = realc ? *(const float4*)(bias + (sub<<2)) : make_float4(0,0,0,0);
  float v0 = fmaf(acc.x, w, b.x), v1 = fmaf(acc.y, w, b.y);
  float v2 = fmaf(acc.z, w, b.z), v3 = fmaf(acc.w, w, b.w);

  float mx = realc ? fmaxf(fmaxf(v0, v1), fmaxf(v2, v3)) : -3.0e38f;
  mx = fmaxf(mx, __shfl_xor(mx, 1)); mx = fmaxf(mx, __shfl_xor(mx, 2));
  mx = fmaxf(mx, __shfl_xor(mx, 4)); mx = fmaxf(mx, __shfl_xor(mx, 8));
  float es = realc ? (__expf(v0-mx) + __expf(v1-mx) + __expf(v2-mx) + __expf(v3-mx)) : 0.f;
  es += __shfl_xor(es, 1); es += __shfl_xor(es, 2);
  es += __shfl_xor(es, 4); es += __shfl_xor(es, 8);
  float ls = __logf(es);
  if (slot == 0 && realc){
    float4 o = make_float4(v0-mx-ls, v1-mx-ls, v2-mx-ls, v3-mx-ls);
    *(float4*)(out + (size_t)node*OUT_ + (sub<<2)) = o;
  }
}

extern "C" void kernel_launch(void* const* d_in, const int* in_sizes, int n_in,
                              void* d_out, int out_size, void* d_ws, size_t ws_size,
                              hipStream_t stream)
{
  const float* x    = (const float*)d_in[0];
  const float* Wl1  = (const float*)d_in[1];
  const float* bl1  = (const float*)d_in[2];
  const float* Wr1  = (const float*)d_in[3];
  const float* br1  = (const float*)d_in[4];
  const float* att1 = (const float*)d_in[5];
  const float* bias1= (const float*)d_in[6];
  const float* Wl2  = (const float*)d_in[7];
  const float* bl2  = (const float*)d_in[8];
  const float* Wr2  = (const float*)d_in[9];
  const float* br2  = (const float*)d_in[10];
  const float* att2 = (const float*)d_in[11];
  const float* bias2= (const float*)d_in[12];
  const int* src1 = (const int*)d_in[13];
  const int* dst1 = (const int*)d_in[14];
  const int* src2 = (const int*)d_in[15];
  const int* dst2 = (const int*)d_in[16];
  const int E1 = in_sizes[13];
  const int E2 = in_sizes[15];
  (void)n_in; (void)out_size; (void)ws_size;

  // ---- workspace layout (bytes), total ~275.5 MB ----
  char* ws = (char*)d_ws;
  unsigned short* xl1  = (unsigned short*)(ws + 0LL);          // bf16 [320000][256]
  unsigned short* xr1  = (unsigned short*)(ws + 163840000LL);  // bf16 [ 80000][256]
  unsigned short* hbuf = (unsigned short*)(ws + 204800000LL);  // bf16 [ 80000][256]
  float* xl2p   = (float*)(ws + 245760000LL);                  // f32  [ 80000][64] padded
  float* xr2p   = (float*)(ws + 266240000LL);                  // f32  [ 16000][64] padded
  int*   perm1  = (int*)  (ws + 270336000LL);                  // int  [800000]
  int*   perm2  = (int*)  (ws + 273536000LL);                  // int  [160000]
  int*   cnt1   = (int*)  (ws + 274176000LL);                  // int  [ 80000] (zeroed)
  int*   cnt2   = (int*)  (ws + 274496000LL);                  // int  [ 16000] (zeroed)
  int*   off1   = (int*)  (ws + 274560000LL);                  // int  [ 80000]
  int*   cur1   = (int*)  (ws + 274880000LL);                  // int  [ 80000]
  int*   off2   = (int*)  (ws + 275200000LL);                  // int  [ 16000]
  int*   cur2   = (int*)  (ws + 275264000LL);                  // int  [ 16000]
  int*   part1  = (int*)  (ws + 275328000LL);                  // int  [   512]
  int*   part2  = (int*)  (ws + 275330048LL);                  // int  [   512]
  unsigned short* Wt1l = (unsigned short*)(ws + 275332096LL);  // bf16 [256][128]
  unsigned short* Wt1r = (unsigned short*)(ws + 275397632LL);  // bf16 [256][128]
  unsigned short* Wt2l = (unsigned short*)(ws + 275463168LL);  // bf16 [ 48][256]
  unsigned short* Wt2r = (unsigned short*)(ws + 275487744LL);  // bf16 [ 48][256]

  hipMemsetAsync(ws + 274176000LL, 0, 384000LL, stream);       // cnt1 + cnt2

  const int nb1 = (N1_ + 255) / 256;   // 313
  const int nb2 = (N2_ + 255) / 256;   // 63

  transpose_all<<<352, 256, 0, stream>>>(Wl1, Wr1, Wl2, Wr2, Wt1l, Wt1r, Wt2l, Wt2r);

  // CSR build for both edge sets (independent of GEMMs)
  hist_both         <<<(E1+E2+255)/256, 256, 0, stream>>>(dst1, dst2, cnt1, cnt2, E1, E2);
  scan_local_both   <<<nb1+nb2, 256, 0, stream>>>(cnt1, cnt2, off1, off2, part1, part2, N1_, N2_, nb1);
  scan_partials_both<<<2, 512, 0, stream>>>(part1, part2, nb1, nb2);
  scan_finalize_both<<<nb1+nb2, 256, 0, stream>>>(off1, off2, part1, part2, cur1, cur2, N1_, N2_, nb1);
  scatter_both      <<<(E1+E2+255)/256, 256, 0, stream>>>(src1, dst1, src2, dst2,
                                                          cur1, cur2, perm1, perm2, E1, E2);

  gemm1_fused<<<N0_/64, 256, 0, stream>>>(x, Wt1l, Wt1r, bl1, br1, xl1, xr1);

  gat_aggregate1<<<(N1_+3)/4, 256, 0, stream>>>(xl1, xr1, off1, cnt1, perm1,
                                                att1, bias1, hbuf, N1_);

  gemm2_fused<<<N1_/64, 256, 0, stream>>>(hbuf, Wt2l, Wt2r, bl2, br2, xl2p, xr2p);

  gat_aggregate2<<<(N2_+3)/4, 256, 0, stream>>>(xl2p, xr2p, off2, cnt2, perm2,
                                                att2, bias2, (float*)d_out, N2_);
}